// Round 1
// baseline (4632.097 us; speedup 1.0000x reference)
//
#include <hip/hip_runtime.h>
#include <math.h>

#define NN 50000
#define NE 800000
#define LDST 68   // activation-tile stride (floats): 68%32=4 -> column writes are 4-way, float4 reads stay 16B-aligned

// ---------------------------------------------------------------------------
// micro GEMM tile: W [K x 96] (LDS, row-major) times inT [K x 64] (LDS, stride LDST)
// thread (fg in [0,32), eg in [0,8)) produces features {fg, fg+32, fg+64} x edges {eg*8 .. eg*8+7}
__device__ __forceinline__ void mm_tile(const float* __restrict__ W,
                                        const float* __restrict__ inT,
                                        int K, int fg, int eg,
                                        float acc0[8], float acc1[8], float acc2[8]) {
  const float* ip = inT + eg * 8;
  #pragma unroll 4
  for (int kk = 0; kk < K; ++kk) {
    const float w0 = W[kk * 96 + fg];
    const float w1 = W[kk * 96 + fg + 32];
    const float w2 = W[kk * 96 + fg + 64];
    const float4 v0 = *(const float4*)(ip + kk * LDST);
    const float4 v1 = *(const float4*)(ip + kk * LDST + 4);
    float a[8] = {v0.x, v0.y, v0.z, v0.w, v1.x, v1.y, v1.z, v1.w};
    #pragma unroll
    for (int t = 0; t < 8; ++t) {
      acc0[t] = fmaf(w0, a[t], acc0[t]);
      acc1[t] = fmaf(w1, a[t], acc1[t]);
      acc2[t] = fmaf(w2, a[t], acc2[t]);
    }
  }
}

// ---------------------------------------------------------------------------
// K0: A = h @ We1[0:96,:], B = h @ We1[96:192,:]   (no bias/relu here)
__global__ void k0_AB(const float* __restrict__ h, const float* __restrict__ We1,
                      float* __restrict__ A, float* __restrict__ B) {
  extern __shared__ float sm[];
  float* Wl = sm;                 // 192*96 = 18432
  float* hT = sm + 18432;         // 96*LDST = 6528
  const int tid = threadIdx.x;
  for (int idx = tid; idx < 18432 / 4; idx += 256)
    ((float4*)Wl)[idx] = ((const float4*)We1)[idx];
  const int base = blockIdx.x * 64;
  const int e = tid >> 2, q = tid & 3;
  const int node = base + e;
  #pragma unroll
  for (int c = 0; c < 6; ++c) {
    const int f = q * 24 + c * 4;
    float4 v = make_float4(0.f, 0.f, 0.f, 0.f);
    if (node < NN) v = *(const float4*)(h + node * 96 + f);
    hT[(f + 0) * LDST + e] = v.x;
    hT[(f + 1) * LDST + e] = v.y;
    hT[(f + 2) * LDST + e] = v.z;
    hT[(f + 3) * LDST + e] = v.w;
  }
  __syncthreads();
  const int fg = tid & 31, eg = tid >> 5;
  float a0[8], a1[8], a2[8];
  #pragma unroll
  for (int t = 0; t < 8; ++t) a0[t] = a1[t] = a2[t] = 0.f;
  mm_tile(Wl, hT, 96, fg, eg, a0, a1, a2);
  #pragma unroll
  for (int t = 0; t < 8; ++t) {
    const int nd = base + eg * 8 + t;
    if (nd < NN) {
      A[nd * 96 + fg]      = a0[t];
      A[nd * 96 + fg + 32] = a1[t];
      A[nd * 96 + fg + 64] = a2[t];
    }
  }
  #pragma unroll
  for (int t = 0; t < 8; ++t) a0[t] = a1[t] = a2[t] = 0.f;
  mm_tile(Wl + 96 * 96, hT, 96, fg, eg, a0, a1, a2);
  #pragma unroll
  for (int t = 0; t < 8; ++t) {
    const int nd = base + eg * 8 + t;
    if (nd < NN) {
      B[nd * 96 + fg]      = a0[t];
      B[nd * 96 + fg + 32] = a1[t];
      B[nd * 96 + fg + 64] = a2[t];
    }
  }
}

// ---------------------------------------------------------------------------
// K1: per-edge MLPs + atomic segment sums
__global__ void k1_edge(const float* __restrict__ x,
                        const float* __restrict__ A, const float* __restrict__ B,
                        const int* __restrict__ ei, const int* __restrict__ ej,
                        const float* __restrict__ We1, const float* __restrict__ be1,
                        const float* __restrict__ We2, const float* __restrict__ be2,
                        const float* __restrict__ Wm, const float* __restrict__ bm,
                        const float* __restrict__ Wx1, const float* __restrict__ bx1,
                        const float* __restrict__ Wx2,
                        float* __restrict__ wmo, float* __restrict__ so,
                        float* __restrict__ co) {
  extern __shared__ float sm[];
  float* We2l = sm;                  // 9216
  float* Wx1l = We2l + 9216;         // 9216
  float* h1T  = Wx1l + 9216;         // 96*LDST
  float* mT   = h1T + 96 * LDST;     // 96*LDST
  float* w192 = mT + 96 * LDST;      // 96
  float* w193 = w192 + 96;
  float* be1l = w193 + 96;
  float* be2l = be1l + 96;
  float* bx1l = be2l + 96;
  float* Wml  = bx1l + 96;
  float* Wx2l = Wml + 96;
  float* gl   = Wx2l + 96;           // 64
  float* phil = gl + 64;             // 64
  float* xjl  = phil + 64;           // 256
  int*   iil  = (int*)(xjl + 256);   // 64

  const int tid = threadIdx.x;
  for (int idx = tid; idx < 9216 / 4; idx += 256) {
    ((float4*)We2l)[idx] = ((const float4*)We2)[idx];
    ((float4*)Wx1l)[idx] = ((const float4*)Wx1)[idx];
  }
  if (tid < 96) {
    w192[tid] = We1[192 * 96 + tid];
    w193[tid] = We1[193 * 96 + tid];
    be1l[tid] = be1[tid];
    be2l[tid] = be2[tid];
    bx1l[tid] = bx1[tid];
    Wml[tid]  = Wm[tid];
    Wx2l[tid] = Wx2[tid];
  }
  const float bms = bm[0];
  const int e = tid >> 2, q = tid & 3;
  const int fg = tid & 31, eg = tid >> 5;
  __syncthreads();

  for (int tile = blockIdx.x; tile < NE / 64; tile += gridDim.x) {
    // ---- gather phase: hid1 = relu(A[i] + B[j] + pn*w192 + pp*w193 + be1)
    const int eidx = tile * 64 + e;
    const int vi = ei[eidx], vj = ej[eidx];
    const float4 xi = *(const float4*)(x + vi * 4);
    const float4 xj = *(const float4*)(x + vj * 4);
    if (q == 0) {
      iil[e] = vi;
      xjl[e * 4 + 0] = xj.x; xjl[e * 4 + 1] = xj.y;
      xjl[e * 4 + 2] = xj.z; xjl[e * 4 + 3] = xj.w;
    }
    const float d0 = xi.x - xj.x, d1 = xi.y - xj.y, d2 = xi.z - xj.z, d3 = xi.w - xj.w;
    const float nrm = d0 * d0 - d1 * d1 - d2 * d2 - d3 * d3;
    const float prd = xi.x * xj.x - xi.y * xj.y - xi.z * xj.z - xi.w * xj.w;
    const float pn = copysignf(logf(fabsf(nrm) + 1.f), nrm);
    const float pp = copysignf(logf(fabsf(prd) + 1.f), prd);
    #pragma unroll
    for (int c = 0; c < 6; ++c) {
      const int f = q * 24 + c * 4;
      const float4 av = *(const float4*)(A + (long)vi * 96 + f);
      const float4 bv = *(const float4*)(B + (long)vj * 96 + f);
      h1T[(f + 0) * LDST + e] = fmaxf(av.x + bv.x + pn * w192[f + 0] + pp * w193[f + 0] + be1l[f + 0], 0.f);
      h1T[(f + 1) * LDST + e] = fmaxf(av.y + bv.y + pn * w192[f + 1] + pp * w193[f + 1] + be1l[f + 1], 0.f);
      h1T[(f + 2) * LDST + e] = fmaxf(av.z + bv.z + pn * w192[f + 2] + pp * w193[f + 2] + be1l[f + 2], 0.f);
      h1T[(f + 3) * LDST + e] = fmaxf(av.w + bv.w + pn * w192[f + 3] + pp * w193[f + 3] + be1l[f + 3], 0.f);
    }
    __syncthreads();

    // ---- m = relu(hid1 @ We2 + be2); g = sigmoid(m.Wm + bm)
    float a0[8], a1[8], a2[8];
    #pragma unroll
    for (int t = 0; t < 8; ++t) a0[t] = a1[t] = a2[t] = 0.f;
    mm_tile(We2l, h1T, 96, fg, eg, a0, a1, a2);
    {
      const float b0 = be2l[fg], b1 = be2l[fg + 32], b2 = be2l[fg + 64];
      const float u0 = Wml[fg],  u1 = Wml[fg + 32],  u2 = Wml[fg + 64];
      #pragma unroll
      for (int t = 0; t < 8; ++t) {
        const float m0 = fmaxf(a0[t] + b0, 0.f);
        const float m1 = fmaxf(a1[t] + b1, 0.f);
        const float m2 = fmaxf(a2[t] + b2, 0.f);
        const int ecol = eg * 8 + t;
        mT[fg * LDST + ecol]        = m0;
        mT[(fg + 32) * LDST + ecol] = m1;
        mT[(fg + 64) * LDST + ecol] = m2;
        float part = m0 * u0 + m1 * u1 + m2 * u2;
        part += __shfl_xor(part, 1);
        part += __shfl_xor(part, 2);
        part += __shfl_xor(part, 4);
        part += __shfl_xor(part, 8);
        part += __shfl_xor(part, 16);
        if (fg == 0) gl[ecol] = 1.f / (1.f + expf(-(part + bms)));
      }
    }
    __syncthreads();

    // ---- phi = relu(m @ Wx1 + bx1) . Wx2
    #pragma unroll
    for (int t = 0; t < 8; ++t) a0[t] = a1[t] = a2[t] = 0.f;
    mm_tile(Wx1l, mT, 96, fg, eg, a0, a1, a2);
    {
      const float b0 = bx1l[fg], b1 = bx1l[fg + 32], b2 = bx1l[fg + 64];
      const float u0 = Wx2l[fg], u1 = Wx2l[fg + 32], u2 = Wx2l[fg + 64];
      #pragma unroll
      for (int t = 0; t < 8; ++t) {
        const float m0 = fmaxf(a0[t] + b0, 0.f);
        const float m1 = fmaxf(a1[t] + b1, 0.f);
        const float m2 = fmaxf(a2[t] + b2, 0.f);
        float part = m0 * u0 + m1 * u1 + m2 * u2;
        part += __shfl_xor(part, 1);
        part += __shfl_xor(part, 2);
        part += __shfl_xor(part, 4);
        part += __shfl_xor(part, 8);
        part += __shfl_xor(part, 16);
        if (fg == 0) phil[eg * 8 + t] = part;
      }
    }
    __syncthreads();

    // ---- scatter: wm[i] += g*m ; s[i] += phi*x_j ; cnt[i] += 1
    {
      const int vi2 = iil[e];
      const float g  = gl[e];
      const float ph = phil[e];
      #pragma unroll
      for (int c = 0; c < 6; ++c) {
        const int f = q * 24 + c * 4;
        #pragma unroll
        for (int s2 = 0; s2 < 4; ++s2)
          atomicAdd(&wmo[(long)vi2 * 96 + f + s2], g * mT[(f + s2) * LDST + e]);
      }
      if (q == 0) {
        atomicAdd(&so[vi2 * 4 + 0], ph * xjl[e * 4 + 0]);
        atomicAdd(&so[vi2 * 4 + 1], ph * xjl[e * 4 + 1]);
        atomicAdd(&so[vi2 * 4 + 2], ph * xjl[e * 4 + 2]);
        atomicAdd(&so[vi2 * 4 + 3], ph * xjl[e * 4 + 3]);
        atomicAdd(&co[vi2], 1.f);
      }
    }
    __syncthreads();
  }
}

// ---------------------------------------------------------------------------
// K3a: tmp = relu([h, wm] @ Wh1 + bh1)
__global__ void k3a_hidden(const float* __restrict__ h, const float* __restrict__ wmv,
                           const float* __restrict__ Wh1, const float* __restrict__ bh1,
                           float* __restrict__ tmp) {
  extern __shared__ float sm[];
  float* Wl  = sm;                   // 192*96
  float* inT = sm + 18432;           // 192*LDST
  float* bl  = inT + 192 * LDST;     // 96
  const int tid = threadIdx.x;
  for (int idx = tid; idx < 18432 / 4; idx += 256)
    ((float4*)Wl)[idx] = ((const float4*)Wh1)[idx];
  if (tid < 96) bl[tid] = bh1[tid];
  const int base = blockIdx.x * 64;
  const int e = tid >> 2, q = tid & 3;
  const int node = base + e;
  #pragma unroll
  for (int c = 0; c < 6; ++c) {
    const int f = q * 24 + c * 4;
    float4 v = make_float4(0.f, 0.f, 0.f, 0.f), w = make_float4(0.f, 0.f, 0.f, 0.f);
    if (node < NN) {
      v = *(const float4*)(h + node * 96 + f);
      w = *(const float4*)(wmv + node * 96 + f);
    }
    inT[(f + 0) * LDST + e] = v.x; inT[(f + 1) * LDST + e] = v.y;
    inT[(f + 2) * LDST + e] = v.z; inT[(f + 3) * LDST + e] = v.w;
    inT[(96 + f + 0) * LDST + e] = w.x; inT[(96 + f + 1) * LDST + e] = w.y;
    inT[(96 + f + 2) * LDST + e] = w.z; inT[(96 + f + 3) * LDST + e] = w.w;
  }
  __syncthreads();
  const int fg = tid & 31, eg = tid >> 5;
  float a0[8], a1[8], a2[8];
  #pragma unroll
  for (int t = 0; t < 8; ++t) a0[t] = a1[t] = a2[t] = 0.f;
  mm_tile(Wl, inT, 192, fg, eg, a0, a1, a2);
  #pragma unroll
  for (int t = 0; t < 8; ++t) {
    const int nd = base + eg * 8 + t;
    if (nd < NN) {
      tmp[nd * 96 + fg]      = fmaxf(a0[t] + bl[fg], 0.f);
      tmp[nd * 96 + fg + 32] = fmaxf(a1[t] + bl[fg + 32], 0.f);
      tmp[nd * 96 + fg + 64] = fmaxf(a2[t] + bl[fg + 64], 0.f);
    }
  }
}

// ---------------------------------------------------------------------------
// K3b: h_out = h + tmp @ Wh2 + bh2 ; x_out = x + C*mean
__global__ void k3b_out(const float* __restrict__ h, const float* __restrict__ tmp,
                        const float* __restrict__ Wh2, const float* __restrict__ bh2,
                        const float* __restrict__ x, const float* __restrict__ sv,
                        const float* __restrict__ cv,
                        float* __restrict__ hout, float* __restrict__ xout) {
  extern __shared__ float sm[];
  float* Wl  = sm;                 // 9216
  float* inT = sm + 9216;          // 96*LDST
  float* bl  = inT + 96 * LDST;    // 96
  const int tid = threadIdx.x;
  for (int idx = tid; idx < 9216 / 4; idx += 256)
    ((float4*)Wl)[idx] = ((const float4*)Wh2)[idx];
  if (tid < 96) bl[tid] = bh2[tid];
  const int base = blockIdx.x * 64;
  const int e = tid >> 2, q = tid & 3;
  const int node = base + e;
  #pragma unroll
  for (int c = 0; c < 6; ++c) {
    const int f = q * 24 + c * 4;
    float4 v = make_float4(0.f, 0.f, 0.f, 0.f);
    if (node < NN) v = *(const float4*)(tmp + node * 96 + f);
    inT[(f + 0) * LDST + e] = v.x; inT[(f + 1) * LDST + e] = v.y;
    inT[(f + 2) * LDST + e] = v.z; inT[(f + 3) * LDST + e] = v.w;
  }
  __syncthreads();
  const int fg = tid & 31, eg = tid >> 5;
  float a0[8], a1[8], a2[8];
  #pragma unroll
  for (int t = 0; t < 8; ++t) a0[t] = a1[t] = a2[t] = 0.f;
  mm_tile(Wl, inT, 96, fg, eg, a0, a1, a2);
  #pragma unroll
  for (int t = 0; t < 8; ++t) {
    const int nd = base + eg * 8 + t;
    if (nd < NN) {
      hout[nd * 96 + fg]      = h[nd * 96 + fg]      + a0[t] + bl[fg];
      hout[nd * 96 + fg + 32] = h[nd * 96 + fg + 32] + a1[t] + bl[fg + 32];
      hout[nd * 96 + fg + 64] = h[nd * 96 + fg + 64] + a2[t] + bl[fg + 64];
    }
  }
  if (node < NN) {
    const float cnt = cv[node];
    const float s4  = sv[node * 4 + q];
    const float mean = cnt > 0.f ? s4 / cnt : 0.f;
    xout[node * 4 + q] = x[node * 4 + q] + 0.005f * mean;
  }
}

// ---------------------------------------------------------------------------
extern "C" void kernel_launch(void* const* d_in, const int* in_sizes, int n_in,
                              void* d_out, int out_size, void* d_ws, size_t ws_size,
                              hipStream_t stream) {
  const float* x   = (const float*)d_in[0];
  const float* h   = (const float*)d_in[1];
  const int*   ei  = (const int*)d_in[2];
  const int*   ej  = (const int*)d_in[3];
  const float* We1 = (const float*)d_in[4];
  const float* be1 = (const float*)d_in[5];
  const float* We2 = (const float*)d_in[6];
  const float* be2 = (const float*)d_in[7];
  const float* Wm  = (const float*)d_in[8];
  const float* bm  = (const float*)d_in[9];
  const float* Wh1 = (const float*)d_in[10];
  const float* bh1 = (const float*)d_in[11];
  const float* Wh2 = (const float*)d_in[12];
  const float* bh2 = (const float*)d_in[13];
  const float* Wx1 = (const float*)d_in[14];
  const float* bx1 = (const float*)d_in[15];
  const float* Wx2 = (const float*)d_in[16];

  float* A   = (float*)d_ws;            // 50000*96
  float* B   = A + 4800000;             // 50000*96
  float* WMv = B + 4800000;             // 50000*96  (atomic target)
  float* Sv  = WMv + 4800000;           // 50000*4   (atomic target)
  float* CNT = Sv + 200000;             // 50000     (atomic target)
  float* TMP = A;                       // reuse A after K1 consumed it
  float* hout = (float*)d_out;
  float* xout = hout + 4800000;

  const int K0_LDS  = (18432 + 96 * LDST) * 4;
  const int K1_LDS  = (9216 * 2 + 96 * LDST * 2 + 96 * 7 + 64 * 2 + 256 + 64) * 4;
  const int K3A_LDS = (18432 + 192 * LDST + 96) * 4;
  const int K3B_LDS = (9216 + 96 * LDST + 96) * 4;

  hipFuncSetAttribute((const void*)k0_AB,     hipFuncAttributeMaxDynamicSharedMemorySize, K0_LDS);
  hipFuncSetAttribute((const void*)k1_edge,   hipFuncAttributeMaxDynamicSharedMemorySize, K1_LDS);
  hipFuncSetAttribute((const void*)k3a_hidden,hipFuncAttributeMaxDynamicSharedMemorySize, K3A_LDS);
  hipFuncSetAttribute((const void*)k3b_out,   hipFuncAttributeMaxDynamicSharedMemorySize, K3B_LDS);

  // zero the atomic accumulators (WMv, Sv, CNT are contiguous)
  hipMemsetAsync(WMv, 0, (size_t)(4800000 + 200000 + 50000) * sizeof(float), stream);

  k0_AB<<<782, 256, K0_LDS, stream>>>(h, We1, A, B);
  k1_edge<<<2500, 256, K1_LDS, stream>>>(x, A, B, ei, ej, We1, be1, We2, be2,
                                         Wm, bm, Wx1, bx1, Wx2, WMv, Sv, CNT);
  k3a_hidden<<<782, 256, K3A_LDS, stream>>>(h, WMv, Wh1, bh1, TMP);
  k3b_out<<<782, 256, K3B_LDS, stream>>>(h, TMP, Wh2, bh2, x, Sv, CNT, hout, xout);
}

// Round 2
// 4419.404 us; speedup vs baseline: 1.0481x; 1.0481x over previous
//
#include <hip/hip_runtime.h>
#include <math.h>

#define NN 50000
#define NE 800000

__device__ __forceinline__ int rfl(int v) { return __builtin_amdgcn_readfirstlane(v); }

// ---------------------------------------------------------------------------
// K0: A = h @ We1[0:96,:], B = h @ We1[96:192,:]
// block = 256 thr = 4 waves; tile = 64 nodes; wave w owns feature block [w*24, w*24+24)
// lane = node-in-tile. Weight index wave-uniform -> s_load (scalar) weights.
__global__ __launch_bounds__(256, 6) void k0_AB(const float* __restrict__ h,
                                                const float* __restrict__ We1,
                                                float* __restrict__ A, float* __restrict__ B) {
  __shared__ float hT[96 * 64];
  const int tid = threadIdx.x, e = tid & 63, wq = tid >> 6;
  const int fb = rfl(wq * 24);
  const int node = blockIdx.x * 64 + e;
  const int nclamp = node < NN ? node : NN - 1;
  #pragma unroll
  for (int c = 0; c < 6; ++c) {
    const int k0 = fb + c * 4;
    const float4 v = *(const float4*)(h + (long)nclamp * 96 + k0);
    hT[(k0 + 0) * 64 + e] = v.x; hT[(k0 + 1) * 64 + e] = v.y;
    hT[(k0 + 2) * 64 + e] = v.z; hT[(k0 + 3) * 64 + e] = v.w;
  }
  __syncthreads();
  float acc[24];
  #pragma unroll
  for (int t = 0; t < 24; ++t) acc[t] = 0.f;
  #pragma unroll 4
  for (int k = 0; k < 96; ++k) {
    const float a = hT[k * 64 + e];
    #pragma unroll
    for (int t = 0; t < 24; ++t) acc[t] = fmaf(a, We1[k * 96 + fb + t], acc[t]);
  }
  if (node < NN) {
    #pragma unroll
    for (int c = 0; c < 6; ++c)
      *(float4*)(A + (long)node * 96 + fb + c * 4) =
          make_float4(acc[c * 4], acc[c * 4 + 1], acc[c * 4 + 2], acc[c * 4 + 3]);
  }
  #pragma unroll
  for (int t = 0; t < 24; ++t) acc[t] = 0.f;
  #pragma unroll 4
  for (int k = 0; k < 96; ++k) {
    const float a = hT[k * 64 + e];
    #pragma unroll
    for (int t = 0; t < 24; ++t) acc[t] = fmaf(a, We1[(96 + k) * 96 + fb + t], acc[t]);
  }
  if (node < NN) {
    #pragma unroll
    for (int c = 0; c < 6; ++c)
      *(float4*)(B + (long)node * 96 + fb + c * 4) =
          make_float4(acc[c * 4], acc[c * 4 + 1], acc[c * 4 + 2], acc[c * 4 + 3]);
  }
}

// ---------------------------------------------------------------------------
// K1: per-edge MLPs + atomic segment sums. One 64-edge tile per block.
// lane = edge, wave = 24-feature block; scalar (s_load) weights; 25.9 KB LDS.
__global__ __launch_bounds__(256, 6) void k1_edge(const float* __restrict__ x,
    const float* __restrict__ A, const float* __restrict__ B,
    const int* __restrict__ ei, const int* __restrict__ ej,
    const float* __restrict__ We1, const float* __restrict__ be1,
    const float* __restrict__ We2, const float* __restrict__ be2,
    const float* __restrict__ Wm, const float* __restrict__ bm,
    const float* __restrict__ Wx1, const float* __restrict__ bx1,
    const float* __restrict__ Wx2,
    float* __restrict__ wmo, float* __restrict__ so, float* __restrict__ co) {
  __shared__ float actT[96 * 64];   // [k][e]; holds h1, then m (in place)
  __shared__ float part4[4 * 64];   // cross-wave dot partials
  __shared__ float gl[64];          // sigmoid gate per edge
  const int tid = threadIdx.x, e = tid & 63, w = tid >> 6;
  const int fb = rfl(w * 24);
  const int eidx = blockIdx.x * 64 + e;
  const int vi = ei[eidx], vj = ej[eidx];
  const float4 xi = *(const float4*)(x + (long)vi * 4);
  const float4 xj = *(const float4*)(x + (long)vj * 4);
  const float d0 = xi.x - xj.x, d1 = xi.y - xj.y, d2 = xi.z - xj.z, d3 = xi.w - xj.w;
  const float nrm = d0 * d0 - d1 * d1 - d2 * d2 - d3 * d3;
  const float prd = xi.x * xj.x - xi.y * xj.y - xi.z * xj.z - xi.w * xj.w;
  const float pn = copysignf(logf(fabsf(nrm) + 1.f), nrm);
  const float pp = copysignf(logf(fabsf(prd) + 1.f), prd);
  const float* Ar = A + (long)vi * 96;
  const float* Br = B + (long)vj * 96;
  #pragma unroll
  for (int c = 0; c < 6; ++c) {
    const int k0 = fb + c * 4;
    const float4 av = *(const float4*)(Ar + k0);
    const float4 bv = *(const float4*)(Br + k0);
    actT[(k0 + 0) * 64 + e] = fmaxf(av.x + bv.x + pn * We1[192 * 96 + k0 + 0] + pp * We1[193 * 96 + k0 + 0] + be1[k0 + 0], 0.f);
    actT[(k0 + 1) * 64 + e] = fmaxf(av.y + bv.y + pn * We1[192 * 96 + k0 + 1] + pp * We1[193 * 96 + k0 + 1] + be1[k0 + 1], 0.f);
    actT[(k0 + 2) * 64 + e] = fmaxf(av.z + bv.z + pn * We1[192 * 96 + k0 + 2] + pp * We1[193 * 96 + k0 + 2] + be1[k0 + 2], 0.f);
    actT[(k0 + 3) * 64 + e] = fmaxf(av.w + bv.w + pn * We1[192 * 96 + k0 + 3] + pp * We1[193 * 96 + k0 + 3] + be1[k0 + 3], 0.f);
  }
  __syncthreads();

  // layer 2: m[fb..fb+23] for edge e
  float m[24];
  #pragma unroll
  for (int t = 0; t < 24; ++t) m[t] = be2[fb + t];
  #pragma unroll 4
  for (int k = 0; k < 96; ++k) {
    const float a = actT[k * 64 + e];
    #pragma unroll
    for (int t = 0; t < 24; ++t) m[t] = fmaf(a, We2[k * 96 + fb + t], m[t]);
  }
  float gpart = 0.f;
  #pragma unroll
  for (int t = 0; t < 24; ++t) { m[t] = fmaxf(m[t], 0.f); gpart = fmaf(m[t], Wm[fb + t], gpart); }
  part4[w * 64 + e] = gpart;
  __syncthreads();

  // store m in place; wave 0 finishes the gate
  #pragma unroll
  for (int t = 0; t < 24; ++t) actT[(fb + t) * 64 + e] = m[t];
  if (tid < 64)
    gl[e] = 1.f / (1.f + expf(-(part4[e] + part4[64 + e] + part4[128 + e] + part4[192 + e] + bm[0])));
  __syncthreads();

  // layer 3: phi-hidden block for edge e
  float hx[24];
  #pragma unroll
  for (int t = 0; t < 24; ++t) hx[t] = bx1[fb + t];
  #pragma unroll 4
  for (int k = 0; k < 96; ++k) {
    const float a = actT[k * 64 + e];
    #pragma unroll
    for (int t = 0; t < 24; ++t) hx[t] = fmaf(a, Wx1[k * 96 + fb + t], hx[t]);
  }
  float ppart = 0.f;
  #pragma unroll
  for (int t = 0; t < 24; ++t) ppart = fmaf(fmaxf(hx[t], 0.f), Wx2[fb + t], ppart);
  part4[w * 64 + e] = ppart;
  __syncthreads();

  // scatter
  const float g = gl[e];
  float* wr = wmo + (long)vi * 96 + fb;
  #pragma unroll
  for (int t = 0; t < 24; ++t) atomicAdd(wr + t, g * m[t]);
  if (tid < 64) {
    const float ph = part4[e] + part4[64 + e] + part4[128 + e] + part4[192 + e];
    atomicAdd(so + (long)vi * 4 + 0, ph * xj.x);
    atomicAdd(so + (long)vi * 4 + 1, ph * xj.y);
    atomicAdd(so + (long)vi * 4 + 2, ph * xj.z);
    atomicAdd(so + (long)vi * 4 + 3, ph * xj.w);
    atomicAdd(co + vi, 1.f);
  }
}

// ---------------------------------------------------------------------------
// K3a: tmp = relu([h, wm] @ Wh1 + bh1)
__global__ __launch_bounds__(256, 3) void k3a_hidden(const float* __restrict__ h,
    const float* __restrict__ wmv, const float* __restrict__ Wh1,
    const float* __restrict__ bh1, float* __restrict__ tmp) {
  __shared__ float inT[192 * 64];
  const int tid = threadIdx.x, e = tid & 63, wq = tid >> 6;
  const int fb = rfl(wq * 24);
  const int node = blockIdx.x * 64 + e;
  const int nclamp = node < NN ? node : NN - 1;
  #pragma unroll
  for (int c = 0; c < 6; ++c) {
    const int k0 = fb + c * 4;
    const float4 v = *(const float4*)(h + (long)nclamp * 96 + k0);
    const float4 u = *(const float4*)(wmv + (long)nclamp * 96 + k0);
    inT[(k0 + 0) * 64 + e] = v.x; inT[(k0 + 1) * 64 + e] = v.y;
    inT[(k0 + 2) * 64 + e] = v.z; inT[(k0 + 3) * 64 + e] = v.w;
    inT[(96 + k0 + 0) * 64 + e] = u.x; inT[(96 + k0 + 1) * 64 + e] = u.y;
    inT[(96 + k0 + 2) * 64 + e] = u.z; inT[(96 + k0 + 3) * 64 + e] = u.w;
  }
  __syncthreads();
  float acc[24];
  #pragma unroll
  for (int t = 0; t < 24; ++t) acc[t] = bh1[fb + t];
  #pragma unroll 4
  for (int k = 0; k < 192; ++k) {
    const float a = inT[k * 64 + e];
    #pragma unroll
    for (int t = 0; t < 24; ++t) acc[t] = fmaf(a, Wh1[k * 96 + fb + t], acc[t]);
  }
  if (node < NN) {
    #pragma unroll
    for (int c = 0; c < 6; ++c)
      *(float4*)(tmp + (long)node * 96 + fb + c * 4) =
          make_float4(fmaxf(acc[c * 4], 0.f), fmaxf(acc[c * 4 + 1], 0.f),
                      fmaxf(acc[c * 4 + 2], 0.f), fmaxf(acc[c * 4 + 3], 0.f));
  }
}

// ---------------------------------------------------------------------------
// K3b: h_out = h + tmp @ Wh2 + bh2 ; x_out = x + C*mean
__global__ __launch_bounds__(256, 6) void k3b_out(const float* __restrict__ h,
    const float* __restrict__ tmp, const float* __restrict__ Wh2,
    const float* __restrict__ bh2, const float* __restrict__ x,
    const float* __restrict__ sv, const float* __restrict__ cv,
    float* __restrict__ hout, float* __restrict__ xout) {
  __shared__ float inT[96 * 64];
  const int tid = threadIdx.x, e = tid & 63, wq = tid >> 6;
  const int fb = rfl(wq * 24);
  const int node = blockIdx.x * 64 + e;
  const int nclamp = node < NN ? node : NN - 1;
  #pragma unroll
  for (int c = 0; c < 6; ++c) {
    const int k0 = fb + c * 4;
    const float4 v = *(const float4*)(tmp + (long)nclamp * 96 + k0);
    inT[(k0 + 0) * 64 + e] = v.x; inT[(k0 + 1) * 64 + e] = v.y;
    inT[(k0 + 2) * 64 + e] = v.z; inT[(k0 + 3) * 64 + e] = v.w;
  }
  __syncthreads();
  float acc[24];
  #pragma unroll
  for (int t = 0; t < 24; ++t) acc[t] = bh2[fb + t];
  #pragma unroll 4
  for (int k = 0; k < 96; ++k) {
    const float a = inT[k * 64 + e];
    #pragma unroll
    for (int t = 0; t < 24; ++t) acc[t] = fmaf(a, Wh2[k * 96 + fb + t], acc[t]);
  }
  if (node < NN) {
    #pragma unroll
    for (int c = 0; c < 6; ++c) {
      const float4 hv = *(const float4*)(h + (long)node * 96 + fb + c * 4);
      *(float4*)(hout + (long)node * 96 + fb + c * 4) =
          make_float4(hv.x + acc[c * 4], hv.y + acc[c * 4 + 1],
                      hv.z + acc[c * 4 + 2], hv.w + acc[c * 4 + 3]);
    }
  }
  if (tid < 64 && node < NN) {
    const float cnt = cv[node];
    const float4 s4 = *(const float4*)(sv + (long)node * 4);
    const float4 xv = *(const float4*)(x + (long)node * 4);
    const float inv = cnt > 0.f ? 1.f / cnt : 0.f;
    *(float4*)(xout + (long)node * 4) =
        make_float4(xv.x + 0.005f * s4.x * inv, xv.y + 0.005f * s4.y * inv,
                    xv.z + 0.005f * s4.z * inv, xv.w + 0.005f * s4.w * inv);
  }
}

// ---------------------------------------------------------------------------
extern "C" void kernel_launch(void* const* d_in, const int* in_sizes, int n_in,
                              void* d_out, int out_size, void* d_ws, size_t ws_size,
                              hipStream_t stream) {
  const float* x   = (const float*)d_in[0];
  const float* h   = (const float*)d_in[1];
  const int*   ei  = (const int*)d_in[2];
  const int*   ej  = (const int*)d_in[3];
  const float* We1 = (const float*)d_in[4];
  const float* be1 = (const float*)d_in[5];
  const float* We2 = (const float*)d_in[6];
  const float* be2 = (const float*)d_in[7];
  const float* Wm  = (const float*)d_in[8];
  const float* bm  = (const float*)d_in[9];
  const float* Wh1 = (const float*)d_in[10];
  const float* bh1 = (const float*)d_in[11];
  const float* Wh2 = (const float*)d_in[12];
  const float* bh2 = (const float*)d_in[13];
  const float* Wx1 = (const float*)d_in[14];
  const float* bx1 = (const float*)d_in[15];
  const float* Wx2 = (const float*)d_in[16];

  float* A   = (float*)d_ws;            // 50000*96
  float* B   = A + 4800000;             // 50000*96
  float* WMv = B + 4800000;             // 50000*96  (atomic target)
  float* Sv  = WMv + 4800000;           // 50000*4   (atomic target)
  float* CNT = Sv + 200000;             // 50000     (atomic target)
  float* TMP = A;                       // reuse A after k1 consumed it
  float* hout = (float*)d_out;
  float* xout = hout + 4800000;

  hipMemsetAsync(WMv, 0, (size_t)(4800000 + 200000 + 50000) * sizeof(float), stream);

  k0_AB<<<782, 256, 0, stream>>>(h, We1, A, B);
  k1_edge<<<NE / 64, 256, 0, stream>>>(x, A, B, ei, ej, We1, be1, We2, be2,
                                       Wm, bm, Wx1, bx1, Wx2, WMv, Sv, CNT);
  k3a_hidden<<<782, 256, 0, stream>>>(h, WMv, Wh1, bh1, TMP);
  k3b_out<<<782, 256, 0, stream>>>(h, TMP, Wh2, bh2, x, Sv, CNT, hout, xout);
}

// Round 3
// 738.048 us; speedup vs baseline: 6.2761x; 5.9880x over previous
//
#include <hip/hip_runtime.h>
#include <math.h>

#define NN 50000
#define NE 800000
#define SLOT 200   // per-edge slot: 96 bf16 gm (192B) + phi f32 (4B) + vj int (4B)

__device__ __forceinline__ int rfl(int v) { return __builtin_amdgcn_readfirstlane(v); }
__device__ __forceinline__ unsigned short f2bf(float f) {
  unsigned u = __float_as_uint(f);
  u += 0x7FFFu + ((u >> 16) & 1u);
  return (unsigned short)(u >> 16);
}
__device__ __forceinline__ unsigned pk2(float a, float b) {
  return (unsigned)f2bf(a) | ((unsigned)f2bf(b) << 16);
}
__device__ __forceinline__ float bflo(unsigned u) { return __uint_as_float(u << 16); }
__device__ __forceinline__ float bfhi(unsigned u) { return __uint_as_float(u & 0xFFFF0000u); }

// ---------------------------------------------------------------------------
// histogram of edge_i
__global__ void khist(const int* __restrict__ ei, int* __restrict__ cnt) {
  const int i = blockIdx.x * 256 + threadIdx.x;
  atomicAdd(&cnt[ei[i]], 1);
}

// single-block exclusive scan of cnt[0..NN) -> base, cursor; base[NN]=NE
__global__ void kscan(const int* __restrict__ cnt, int* __restrict__ base,
                      int* __restrict__ cursor) {
  __shared__ int ps[1024];
  const int t = threadIdx.x;
  const int st = t * 49;
  int s = 0;
  for (int i = 0; i < 49; ++i) { const int idx = st + i; s += (idx < NN) ? cnt[idx] : 0; }
  ps[t] = s;
  __syncthreads();
  for (int off = 1; off < 1024; off <<= 1) {
    const int v = (t >= off) ? ps[t - off] : 0;
    __syncthreads();
    ps[t] += v;
    __syncthreads();
  }
  int ex = (t == 0) ? 0 : ps[t - 1];
  for (int i = 0; i < 49; ++i) {
    const int idx = st + i;
    if (idx < NN) { base[idx] = ex; cursor[idx] = ex; ex += cnt[idx]; }
  }
  if (t == 1023) base[NN] = NE;
}

// ---------------------------------------------------------------------------
// K0: A = h @ We1[0:96,:], B = h @ We1[96:192,:]  (bf16 outputs)
__global__ __launch_bounds__(256, 6) void k0_AB(const float* __restrict__ h,
                                                const float* __restrict__ We1,
                                                unsigned short* __restrict__ Abf,
                                                unsigned short* __restrict__ Bbf) {
  __shared__ float hT[96 * 64];
  const int tid = threadIdx.x, e = tid & 63, wq = tid >> 6;
  const int fb = rfl(wq * 24);
  const int node = blockIdx.x * 64 + e;
  const int nclamp = node < NN ? node : NN - 1;
  #pragma unroll
  for (int c = 0; c < 6; ++c) {
    const int k0 = fb + c * 4;
    const float4 v = *(const float4*)(h + (long)nclamp * 96 + k0);
    hT[(k0 + 0) * 64 + e] = v.x; hT[(k0 + 1) * 64 + e] = v.y;
    hT[(k0 + 2) * 64 + e] = v.z; hT[(k0 + 3) * 64 + e] = v.w;
  }
  __syncthreads();
  float acc[24];
  #pragma unroll
  for (int t = 0; t < 24; ++t) acc[t] = 0.f;
  #pragma unroll 4
  for (int k = 0; k < 96; ++k) {
    const float a = hT[k * 64 + e];
    #pragma unroll
    for (int t = 0; t < 24; ++t) acc[t] = fmaf(a, We1[k * 96 + fb + t], acc[t]);
  }
  if (node < NN) {
    unsigned* dst = (unsigned*)(Abf + (size_t)node * 96 + fb);
    #pragma unroll
    for (int p = 0; p < 12; ++p) dst[p] = pk2(acc[2 * p], acc[2 * p + 1]);
  }
  #pragma unroll
  for (int t = 0; t < 24; ++t) acc[t] = 0.f;
  #pragma unroll 4
  for (int k = 0; k < 96; ++k) {
    const float a = hT[k * 64 + e];
    #pragma unroll
    for (int t = 0; t < 24; ++t) acc[t] = fmaf(a, We1[(96 + k) * 96 + fb + t], acc[t]);
  }
  if (node < NN) {
    unsigned* dst = (unsigned*)(Bbf + (size_t)node * 96 + fb);
    #pragma unroll
    for (int p = 0; p < 12; ++p) dst[p] = pk2(acc[2 * p], acc[2 * p + 1]);
  }
}

// ---------------------------------------------------------------------------
// K1: per-edge MLPs; writes per-edge payload into CSR slot (no f32 atomics)
__global__ __launch_bounds__(256, 6) void k1_edge(const float* __restrict__ x,
    const unsigned short* __restrict__ Abf, const unsigned short* __restrict__ Bbf,
    const int* __restrict__ ei, const int* __restrict__ ej,
    const float* __restrict__ We1, const float* __restrict__ be1,
    const float* __restrict__ We2, const float* __restrict__ be2,
    const float* __restrict__ Wm, const float* __restrict__ bm,
    const float* __restrict__ Wx1, const float* __restrict__ bx1,
    const float* __restrict__ Wx2,
    int* __restrict__ cursor, char* __restrict__ gmbuf) {
  __shared__ float actT[96 * 64];
  __shared__ float part4[4 * 64];
  __shared__ float gl[64];
  __shared__ int posl[64];
  const int tid = threadIdx.x, e = tid & 63, w = tid >> 6;
  const int fb = rfl(w * 24);
  const int eidx = blockIdx.x * 64 + e;
  const int vi = ei[eidx], vj = ej[eidx];
  const float4 xi = *(const float4*)(x + (long)vi * 4);
  const float4 xj = *(const float4*)(x + (long)vj * 4);
  if (tid < 64) posl[e] = atomicAdd(&cursor[vi], 1);
  const float d0 = xi.x - xj.x, d1 = xi.y - xj.y, d2 = xi.z - xj.z, d3 = xi.w - xj.w;
  const float nrm = d0 * d0 - d1 * d1 - d2 * d2 - d3 * d3;
  const float prd = xi.x * xj.x - xi.y * xj.y - xi.z * xj.z - xi.w * xj.w;
  const float pn = copysignf(logf(fabsf(nrm) + 1.f), nrm);
  const float pp = copysignf(logf(fabsf(prd) + 1.f), prd);
  {
    const uint4* Ar = (const uint4*)(Abf + (size_t)vi * 96 + fb);
    const uint4* Br = (const uint4*)(Bbf + (size_t)vj * 96 + fb);
    const uint4 A0 = Ar[0], A1 = Ar[1], A2 = Ar[2];
    const uint4 B0 = Br[0], B1 = Br[1], B2 = Br[2];
    unsigned ua[12], ub[12];
    ua[0]=A0.x; ua[1]=A0.y; ua[2]=A0.z; ua[3]=A0.w; ua[4]=A1.x; ua[5]=A1.y;
    ua[6]=A1.z; ua[7]=A1.w; ua[8]=A2.x; ua[9]=A2.y; ua[10]=A2.z; ua[11]=A2.w;
    ub[0]=B0.x; ub[1]=B0.y; ub[2]=B0.z; ub[3]=B0.w; ub[4]=B1.x; ub[5]=B1.y;
    ub[6]=B1.z; ub[7]=B1.w; ub[8]=B2.x; ub[9]=B2.y; ub[10]=B2.z; ub[11]=B2.w;
    #pragma unroll
    for (int p = 0; p < 12; ++p) {
      const int f = fb + 2 * p;
      actT[f * 64 + e] =
          fmaxf(bflo(ua[p]) + bflo(ub[p]) + pn * We1[192 * 96 + f] + pp * We1[193 * 96 + f] + be1[f], 0.f);
      actT[(f + 1) * 64 + e] =
          fmaxf(bfhi(ua[p]) + bfhi(ub[p]) + pn * We1[192 * 96 + f + 1] + pp * We1[193 * 96 + f + 1] + be1[f + 1], 0.f);
    }
  }
  __syncthreads();

  // layer 2: m
  float m[24];
  #pragma unroll
  for (int t = 0; t < 24; ++t) m[t] = be2[fb + t];
  #pragma unroll 4
  for (int k = 0; k < 96; ++k) {
    const float a = actT[k * 64 + e];
    #pragma unroll
    for (int t = 0; t < 24; ++t) m[t] = fmaf(a, We2[k * 96 + fb + t], m[t]);
  }
  float gpart = 0.f;
  #pragma unroll
  for (int t = 0; t < 24; ++t) { m[t] = fmaxf(m[t], 0.f); gpart = fmaf(m[t], Wm[fb + t], gpart); }
  part4[w * 64 + e] = gpart;
  __syncthreads();

  #pragma unroll
  for (int t = 0; t < 24; ++t) actT[(fb + t) * 64 + e] = m[t];
  if (tid < 64)
    gl[e] = 1.f / (1.f + expf(-(part4[e] + part4[64 + e] + part4[128 + e] + part4[192 + e] + bm[0])));
  __syncthreads();

  // layer 3: phi hidden
  float hx[24];
  #pragma unroll
  for (int t = 0; t < 24; ++t) hx[t] = bx1[fb + t];
  #pragma unroll 4
  for (int k = 0; k < 96; ++k) {
    const float a = actT[k * 64 + e];
    #pragma unroll
    for (int t = 0; t < 24; ++t) hx[t] = fmaf(a, Wx1[k * 96 + fb + t], hx[t]);
  }
  float ppart = 0.f;
  #pragma unroll
  for (int t = 0; t < 24; ++t) ppart = fmaf(fmaxf(hx[t], 0.f), Wx2[fb + t], ppart);
  part4[w * 64 + e] = ppart;
  __syncthreads();

  // write payload to CSR slot (plain stores)
  {
    const float g = gl[e];
    char* slot = gmbuf + (size_t)posl[e] * SLOT;
    unsigned pk[12];
    #pragma unroll
    for (int c = 0; c < 12; ++c) pk[c] = pk2(g * m[2 * c], g * m[2 * c + 1]);
    uint2* dst = (uint2*)(slot + w * 48);
    dst[0] = make_uint2(pk[0], pk[1]);
    dst[1] = make_uint2(pk[2], pk[3]);
    dst[2] = make_uint2(pk[4], pk[5]);
    dst[3] = make_uint2(pk[6], pk[7]);
    dst[4] = make_uint2(pk[8], pk[9]);
    dst[5] = make_uint2(pk[10], pk[11]);
    if (tid < 64) {
      const float ph = part4[e] + part4[64 + e] + part4[128 + e] + part4[192 + e];
      *(uint2*)(slot + 192) = make_uint2(__float_as_uint(ph), (unsigned)vj);
    }
  }
}

// ---------------------------------------------------------------------------
// kred: one wave per node; sum its contiguous slot run
__global__ __launch_bounds__(256, 8) void kred(const float* __restrict__ x,
    const char* __restrict__ gmbuf, const int* __restrict__ base,
    float* __restrict__ wm, float* __restrict__ svm) {
  const int t = threadIdx.x, l = t & 63;
  const int node = blockIdx.x * 4 + (t >> 6);
  const int b0 = base[node], b1 = base[node + 1];
  float a0 = 0.f, a1 = 0.f, sx = 0.f;
  for (int s = b0; s < b1; ++s) {
    const char* slot = gmbuf + (size_t)s * SLOT;
    if (l < 48) {
      const unsigned u = *(const unsigned*)(slot + l * 4);
      a0 += bflo(u); a1 += bfhi(u);
    } else if (l < 52) {
      const float phi = *(const float*)(slot + 192);
      const int vj = *(const int*)(slot + 196);
      sx = fmaf(phi, x[(size_t)vj * 4 + (l - 48)], sx);
    }
  }
  if (l < 48) {
    *(float2*)(wm + (size_t)node * 96 + 2 * l) = make_float2(a0, a1);
  } else if (l < 52) {
    svm[(size_t)node * 4 + (l - 48)] = (b1 > b0) ? sx / (float)(b1 - b0) : 0.f;
  }
}

// ---------------------------------------------------------------------------
// K3a: tmp = relu([h, wm] @ Wh1 + bh1)
__global__ __launch_bounds__(256, 3) void k3a_hidden(const float* __restrict__ h,
    const float* __restrict__ wmv, const float* __restrict__ Wh1,
    const float* __restrict__ bh1, float* __restrict__ tmp) {
  __shared__ float inT[192 * 64];
  const int tid = threadIdx.x, e = tid & 63, wq = tid >> 6;
  const int fb = rfl(wq * 24);
  const int node = blockIdx.x * 64 + e;
  const int nclamp = node < NN ? node : NN - 1;
  #pragma unroll
  for (int c = 0; c < 6; ++c) {
    const int k0 = fb + c * 4;
    const float4 v = *(const float4*)(h + (long)nclamp * 96 + k0);
    const float4 u = *(const float4*)(wmv + (long)nclamp * 96 + k0);
    inT[(k0 + 0) * 64 + e] = v.x; inT[(k0 + 1) * 64 + e] = v.y;
    inT[(k0 + 2) * 64 + e] = v.z; inT[(k0 + 3) * 64 + e] = v.w;
    inT[(96 + k0 + 0) * 64 + e] = u.x; inT[(96 + k0 + 1) * 64 + e] = u.y;
    inT[(96 + k0 + 2) * 64 + e] = u.z; inT[(96 + k0 + 3) * 64 + e] = u.w;
  }
  __syncthreads();
  float acc[24];
  #pragma unroll
  for (int t = 0; t < 24; ++t) acc[t] = bh1[fb + t];
  #pragma unroll 4
  for (int k = 0; k < 192; ++k) {
    const float a = inT[k * 64 + e];
    #pragma unroll
    for (int t = 0; t < 24; ++t) acc[t] = fmaf(a, Wh1[k * 96 + fb + t], acc[t]);
  }
  if (node < NN) {
    #pragma unroll
    for (int c = 0; c < 6; ++c)
      *(float4*)(tmp + (long)node * 96 + fb + c * 4) =
          make_float4(fmaxf(acc[c * 4], 0.f), fmaxf(acc[c * 4 + 1], 0.f),
                      fmaxf(acc[c * 4 + 2], 0.f), fmaxf(acc[c * 4 + 3], 0.f));
  }
}

// ---------------------------------------------------------------------------
// K3b: h_out = h + tmp @ Wh2 + bh2 ; x_out = x + C*mean
__global__ __launch_bounds__(256, 6) void k3b_out(const float* __restrict__ h,
    const float* __restrict__ tmp, const float* __restrict__ Wh2,
    const float* __restrict__ bh2, const float* __restrict__ x,
    const float* __restrict__ svm,
    float* __restrict__ hout, float* __restrict__ xout) {
  __shared__ float inT[96 * 64];
  const int tid = threadIdx.x, e = tid & 63, wq = tid >> 6;
  const int fb = rfl(wq * 24);
  const int node = blockIdx.x * 64 + e;
  const int nclamp = node < NN ? node : NN - 1;
  #pragma unroll
  for (int c = 0; c < 6; ++c) {
    const int k0 = fb + c * 4;
    const float4 v = *(const float4*)(tmp + (long)nclamp * 96 + k0);
    inT[(k0 + 0) * 64 + e] = v.x; inT[(k0 + 1) * 64 + e] = v.y;
    inT[(k0 + 2) * 64 + e] = v.z; inT[(k0 + 3) * 64 + e] = v.w;
  }
  __syncthreads();
  float acc[24];
  #pragma unroll
  for (int t = 0; t < 24; ++t) acc[t] = bh2[fb + t];
  #pragma unroll 4
  for (int k = 0; k < 96; ++k) {
    const float a = inT[k * 64 + e];
    #pragma unroll
    for (int t = 0; t < 24; ++t) acc[t] = fmaf(a, Wh2[k * 96 + fb + t], acc[t]);
  }
  if (node < NN) {
    #pragma unroll
    for (int c = 0; c < 6; ++c) {
      const float4 hv = *(const float4*)(h + (long)node * 96 + fb + c * 4);
      *(float4*)(hout + (long)node * 96 + fb + c * 4) =
          make_float4(hv.x + acc[c * 4], hv.y + acc[c * 4 + 1],
                      hv.z + acc[c * 4 + 2], hv.w + acc[c * 4 + 3]);
    }
  }
  if (tid < 64 && node < NN) {
    const float4 s4 = *(const float4*)(svm + (long)node * 4);
    const float4 xv = *(const float4*)(x + (long)node * 4);
    *(float4*)(xout + (long)node * 4) =
        make_float4(xv.x + 0.005f * s4.x, xv.y + 0.005f * s4.y,
                    xv.z + 0.005f * s4.z, xv.w + 0.005f * s4.w);
  }
}

// ---------------------------------------------------------------------------
extern "C" void kernel_launch(void* const* d_in, const int* in_sizes, int n_in,
                              void* d_out, int out_size, void* d_ws, size_t ws_size,
                              hipStream_t stream) {
  const float* x   = (const float*)d_in[0];
  const float* h   = (const float*)d_in[1];
  const int*   ei  = (const int*)d_in[2];
  const int*   ej  = (const int*)d_in[3];
  const float* We1 = (const float*)d_in[4];
  const float* be1 = (const float*)d_in[5];
  const float* We2 = (const float*)d_in[6];
  const float* be2 = (const float*)d_in[7];
  const float* Wm  = (const float*)d_in[8];
  const float* bm  = (const float*)d_in[9];
  const float* Wh1 = (const float*)d_in[10];
  const float* bh1 = (const float*)d_in[11];
  const float* Wh2 = (const float*)d_in[12];
  const float* bh2 = (const float*)d_in[13];
  const float* Wx1 = (const float*)d_in[14];
  const float* bx1 = (const float*)d_in[15];
  const float* Wx2 = (const float*)d_in[16];

  char* w = (char*)d_ws;
  unsigned short* Abf = (unsigned short*)w;                  //  9.6 MB
  unsigned short* Bbf = (unsigned short*)(w + 9600000);      //  9.6 MB
  float* WMv  = (float*)(w + 19200000);                      // 19.2 MB
  float* SvM  = (float*)(w + 38400000);                      //  0.8 MB
  int*   cnt  = (int*)(w + 39200000);                        //  0.2 MB
  int*   base = (int*)(w + 39400000);                        //  0.2 MB (+4)
  int*   curs = (int*)(w + 39600064);                        //  0.2 MB
  char*  gmb  = w + 39800128;                                // 160  MB
  float* TMP  = (float*)w;                                   // alias Abf/Bbf after k1

  float* hout = (float*)d_out;
  float* xout = hout + 4800000;

  hipMemsetAsync(cnt, 0, NN * sizeof(int), stream);
  khist<<<NE / 256, 256, 0, stream>>>(ei, cnt);
  kscan<<<1, 1024, 0, stream>>>(cnt, base, curs);
  k0_AB<<<782, 256, 0, stream>>>(h, We1, Abf, Bbf);
  k1_edge<<<NE / 64, 256, 0, stream>>>(x, Abf, Bbf, ei, ej, We1, be1, We2, be2,
                                       Wm, bm, Wx1, bx1, Wx2, curs, gmb);
  kred<<<NN / 4, 256, 0, stream>>>(x, gmb, base, WMv, SvM);
  k3a_hidden<<<782, 256, 0, stream>>>(h, WMv, Wh1, bh1, TMP);
  k3b_out<<<782, 256, 0, stream>>>(h, TMP, Wh2, bh2, x, SvM, hout, xout);
}

// Round 4
// 623.472 us; speedup vs baseline: 7.4295x; 1.1838x over previous
//
#include <hip/hip_runtime.h>
#include <math.h>

#define NN 50000
#define NE 800000
#define SLOT 192   // per-edge payload: 96 bf16 (g*m). phi/vj live in side arrays.

typedef __attribute__((ext_vector_type(8))) short short8v;
typedef __attribute__((ext_vector_type(4))) float f32x4;

__device__ __forceinline__ int rfl(int v) { return __builtin_amdgcn_readfirstlane(v); }
__device__ __forceinline__ unsigned short f2bf(float f) {
  unsigned u = __float_as_uint(f);
  u += 0x7FFFu + ((u >> 16) & 1u);
  return (unsigned short)(u >> 16);
}
__device__ __forceinline__ unsigned pk2(float a, float b) {
  return (unsigned)f2bf(a) | ((unsigned)f2bf(b) << 16);
}
__device__ __forceinline__ float bflo(unsigned u) { return __uint_as_float(u << 16); }
__device__ __forceinline__ float bfhi(unsigned u) { return __uint_as_float(u & 0xFFFF0000u); }

// ---------------------------------------------------------------------------
__global__ void khist(const int* __restrict__ ei, int* __restrict__ cnt) {
  const int i = blockIdx.x * 256 + threadIdx.x;
  atomicAdd(&cnt[ei[i]], 1);
}

__global__ void kscan(const int* __restrict__ cnt, int* __restrict__ base,
                      int* __restrict__ cursor) {
  __shared__ int ps[1024];
  const int t = threadIdx.x;
  const int st = t * 49;
  int s = 0;
  for (int i = 0; i < 49; ++i) { const int idx = st + i; s += (idx < NN) ? cnt[idx] : 0; }
  ps[t] = s;
  __syncthreads();
  for (int off = 1; off < 1024; off <<= 1) {
    const int v = (t >= off) ? ps[t - off] : 0;
    __syncthreads();
    ps[t] += v;
    __syncthreads();
  }
  int ex = (t == 0) ? 0 : ps[t - 1];
  for (int i = 0; i < 49; ++i) {
    const int idx = st + i;
    if (idx < NN) { base[idx] = ex; cursor[idx] = ex; ex += cnt[idx]; }
  }
  if (t == 1023) base[NN] = NE;
}

// ---------------------------------------------------------------------------
// pack We2 / Wx1 into MFMA B-fragment-major bf16: frag idx = ((tk*6+tn)*64+lane)*8+j
// B[k][n]: col n = tn*16 + (lane&15), k = tk*32 + (lane>>4)*8 + j
__global__ void kwprep(const float* __restrict__ We2, const float* __restrict__ Wx1,
                       unsigned short* __restrict__ We2p, unsigned short* __restrict__ Wx1p) {
  const int t = blockIdx.x * 256 + threadIdx.x;   // 0..9215
  const int j = t & 7, lane = (t >> 3) & 63, tile = t >> 9;
  const int tk = tile / 6, tn = tile % 6;
  const int k = tk * 32 + (lane >> 4) * 8 + j;
  const int n = tn * 16 + (lane & 15);
  We2p[t] = f2bf(We2[k * 96 + n]);
  Wx1p[t] = f2bf(Wx1[k * 96 + n]);
}

// ---------------------------------------------------------------------------
// K0: A = h @ We1[0:96,:], B = h @ We1[96:192,:]  (bf16 outputs) — unchanged
__global__ __launch_bounds__(256, 6) void k0_AB(const float* __restrict__ h,
                                                const float* __restrict__ We1,
                                                unsigned short* __restrict__ Abf,
                                                unsigned short* __restrict__ Bbf) {
  __shared__ float hT[96 * 64];
  const int tid = threadIdx.x, e = tid & 63, wq = tid >> 6;
  const int fb = rfl(wq * 24);
  const int node = blockIdx.x * 64 + e;
  const int nclamp = node < NN ? node : NN - 1;
  #pragma unroll
  for (int c = 0; c < 6; ++c) {
    const int k0 = fb + c * 4;
    const float4 v = *(const float4*)(h + (long)nclamp * 96 + k0);
    hT[(k0 + 0) * 64 + e] = v.x; hT[(k0 + 1) * 64 + e] = v.y;
    hT[(k0 + 2) * 64 + e] = v.z; hT[(k0 + 3) * 64 + e] = v.w;
  }
  __syncthreads();
  float acc[24];
  #pragma unroll
  for (int t = 0; t < 24; ++t) acc[t] = 0.f;
  #pragma unroll 4
  for (int k = 0; k < 96; ++k) {
    const float a = hT[k * 64 + e];
    #pragma unroll
    for (int t = 0; t < 24; ++t) acc[t] = fmaf(a, We1[k * 96 + fb + t], acc[t]);
  }
  if (node < NN) {
    unsigned* dst = (unsigned*)(Abf + (size_t)node * 96 + fb);
    #pragma unroll
    for (int p = 0; p < 12; ++p) dst[p] = pk2(acc[2 * p], acc[2 * p + 1]);
  }
  #pragma unroll
  for (int t = 0; t < 24; ++t) acc[t] = 0.f;
  #pragma unroll 4
  for (int k = 0; k < 96; ++k) {
    const float a = hT[k * 64 + e];
    #pragma unroll
    for (int t = 0; t < 24; ++t) acc[t] = fmaf(a, We1[(96 + k) * 96 + fb + t], acc[t]);
  }
  if (node < NN) {
    unsigned* dst = (unsigned*)(Bbf + (size_t)node * 96 + fb);
    #pragma unroll
    for (int p = 0; p < 12; ++p) dst[p] = pk2(acc[2 * p], acc[2 * p + 1]);
  }
}

// ---------------------------------------------------------------------------
// K1: per-edge MLPs via MFMA. 64 edges/block, 4 waves; wave w owns edge rows w*16..+15.
__global__ __launch_bounds__(256, 4) void k1_edge(const float* __restrict__ x,
    const unsigned short* __restrict__ Abf, const unsigned short* __restrict__ Bbf,
    const int* __restrict__ ei, const int* __restrict__ ej,
    const float* __restrict__ We1, const float* __restrict__ be1,
    const unsigned short* __restrict__ We2p, const float* __restrict__ be2,
    const float* __restrict__ Wm, const float* __restrict__ bm,
    const unsigned short* __restrict__ Wx1p, const float* __restrict__ bx1,
    const float* __restrict__ Wx2,
    int* __restrict__ cursor, char* __restrict__ gmbuf,
    float* __restrict__ phiv, int* __restrict__ vjv) {
  __shared__ unsigned short actT[64 * 104];  // [edge][feat] bf16, row stride 104
  __shared__ float gl[64];
  __shared__ float phil[64];
  __shared__ int posl[64];
  __shared__ int vjl[64];

  const int tid = threadIdx.x;
  const float bm0 = bm[0];

  // ---- phase 0: gather + h1 (thread: edge e2 = tid&63, feature block fb)
  {
    const int e2 = tid & 63, fb = (tid >> 6) * 24;
    const int eidx = blockIdx.x * 64 + e2;
    const int vi = ei[eidx], vj = ej[eidx];
    if (tid < 64) { posl[e2] = atomicAdd(&cursor[ei[blockIdx.x * 64 + e2]], 1); vjl[e2] = ej[blockIdx.x * 64 + e2]; }
    const float4 xi = *(const float4*)(x + (long)vi * 4);
    const float4 xj = *(const float4*)(x + (long)vj * 4);
    const float d0 = xi.x - xj.x, d1 = xi.y - xj.y, d2 = xi.z - xj.z, d3 = xi.w - xj.w;
    const float nrm = d0 * d0 - d1 * d1 - d2 * d2 - d3 * d3;
    const float prd = xi.x * xj.x - xi.y * xj.y - xi.z * xj.z - xi.w * xj.w;
    const float pn = copysignf(logf(fabsf(nrm) + 1.f), nrm);
    const float pp = copysignf(logf(fabsf(prd) + 1.f), prd);
    const uint4* Ar = (const uint4*)(Abf + (size_t)vi * 96 + fb);
    const uint4* Br = (const uint4*)(Bbf + (size_t)vj * 96 + fb);
    const uint4 A0 = Ar[0], A1 = Ar[1], A2 = Ar[2];
    const uint4 B0 = Br[0], B1 = Br[1], B2 = Br[2];
    unsigned ua[12], ub[12];
    ua[0]=A0.x; ua[1]=A0.y; ua[2]=A0.z; ua[3]=A0.w; ua[4]=A1.x; ua[5]=A1.y;
    ua[6]=A1.z; ua[7]=A1.w; ua[8]=A2.x; ua[9]=A2.y; ua[10]=A2.z; ua[11]=A2.w;
    ub[0]=B0.x; ub[1]=B0.y; ub[2]=B0.z; ub[3]=B0.w; ub[4]=B1.x; ub[5]=B1.y;
    ub[6]=B1.z; ub[7]=B1.w; ub[8]=B2.x; ub[9]=B2.y; ub[10]=B2.z; ub[11]=B2.w;
    unsigned* arow = (unsigned*)actT + e2 * 52 + fb / 2;
    #pragma unroll
    for (int p = 0; p < 12; ++p) {
      const int f = fb + 2 * p;
      const float lo = fmaxf(bflo(ua[p]) + bflo(ub[p]) + pn * We1[192 * 96 + f] + pp * We1[193 * 96 + f] + be1[f], 0.f);
      const float hi = fmaxf(bfhi(ua[p]) + bfhi(ub[p]) + pn * We1[192 * 96 + f + 1] + pp * We1[193 * 96 + f + 1] + be1[f + 1], 0.f);
      arow[p] = pk2(lo, hi);
    }
  }
  __syncthreads();

  const int l = tid & 63, w = tid >> 6;
  const int cg = l & 15, rg = l >> 4;
  const short8v* Wp2 = (const short8v*)We2p;
  const short8v* Wpx = (const short8v*)Wx1p;

  // ---- GEMM2: m = relu(h1 @ We2 + be2); gate partials
  {
    const unsigned short* ar = actT + (w * 16 + cg) * 104;
    const short8v af0 = *(const short8v*)(ar + rg * 8);
    const short8v af1 = *(const short8v*)(ar + 32 + rg * 8);
    const short8v af2 = *(const short8v*)(ar + 64 + rg * 8);
    f32x4 acc[6];
    #pragma unroll
    for (int tn = 0; tn < 6; ++tn) acc[tn] = (f32x4){0.f, 0.f, 0.f, 0.f};
    #pragma unroll
    for (int tn = 0; tn < 6; ++tn) {
      acc[tn] = __builtin_amdgcn_mfma_f32_16x16x32_bf16(af0, Wp2[(0 * 6 + tn) * 64 + l], acc[tn], 0, 0, 0);
      acc[tn] = __builtin_amdgcn_mfma_f32_16x16x32_bf16(af1, Wp2[(1 * 6 + tn) * 64 + l], acc[tn], 0, 0, 0);
      acc[tn] = __builtin_amdgcn_mfma_f32_16x16x32_bf16(af2, Wp2[(2 * 6 + tn) * 64 + l], acc[tn], 0, 0, 0);
    }
    float gp[4] = {0.f, 0.f, 0.f, 0.f};
    #pragma unroll
    for (int tn = 0; tn < 6; ++tn) {
      const int col = tn * 16 + cg;
      const float b = be2[col], wmw = Wm[col];
      #pragma unroll
      for (int r = 0; r < 4; ++r) {
        const float v = fmaxf(acc[tn][r] + b, 0.f);
        gp[r] = fmaf(v, wmw, gp[r]);
        actT[(w * 16 + rg * 4 + r) * 104 + col] = (short)f2bf(v);
      }
    }
    #pragma unroll
    for (int r = 0; r < 4; ++r) {
      float s = gp[r];
      s += __shfl_xor(s, 1); s += __shfl_xor(s, 2);
      s += __shfl_xor(s, 4); s += __shfl_xor(s, 8);
      if (cg == 0) gl[w * 16 + rg * 4 + r] = 1.f / (1.f + expf(-(s + bm0)));
    }
  }
  __syncthreads();

  // ---- GEMM3: phi = relu(m @ Wx1 + bx1) . Wx2
  {
    const unsigned short* mr = actT + (w * 16 + cg) * 104;
    const short8v mf0 = *(const short8v*)(mr + rg * 8);
    const short8v mf1 = *(const short8v*)(mr + 32 + rg * 8);
    const short8v mf2 = *(const short8v*)(mr + 64 + rg * 8);
    f32x4 acc[6];
    #pragma unroll
    for (int tn = 0; tn < 6; ++tn) acc[tn] = (f32x4){0.f, 0.f, 0.f, 0.f};
    #pragma unroll
    for (int tn = 0; tn < 6; ++tn) {
      acc[tn] = __builtin_amdgcn_mfma_f32_16x16x32_bf16(mf0, Wpx[(0 * 6 + tn) * 64 + l], acc[tn], 0, 0, 0);
      acc[tn] = __builtin_amdgcn_mfma_f32_16x16x32_bf16(mf1, Wpx[(1 * 6 + tn) * 64 + l], acc[tn], 0, 0, 0);
      acc[tn] = __builtin_amdgcn_mfma_f32_16x16x32_bf16(mf2, Wpx[(2 * 6 + tn) * 64 + l], acc[tn], 0, 0, 0);
    }
    float pp2[4] = {0.f, 0.f, 0.f, 0.f};
    #pragma unroll
    for (int tn = 0; tn < 6; ++tn) {
      const int col = tn * 16 + cg;
      const float b = bx1[col], wxw = Wx2[col];
      #pragma unroll
      for (int r = 0; r < 4; ++r)
        pp2[r] = fmaf(fmaxf(acc[tn][r] + b, 0.f), wxw, pp2[r]);
    }
    #pragma unroll
    for (int r = 0; r < 4; ++r) {
      float s = pp2[r];
      s += __shfl_xor(s, 1); s += __shfl_xor(s, 2);
      s += __shfl_xor(s, 4); s += __shfl_xor(s, 8);
      if (cg == 0) phil[w * 16 + rg * 4 + r] = s;
    }
  }
  __syncthreads();

  // ---- payload: 4 threads per edge write 192B of g*m (bf16) + side phi/vj
  {
    const int e = tid >> 2, q = tid & 3;
    const float g = gl[e];
    const uint4* mrow = (const uint4*)((const unsigned*)actT + e * 52 + q * 12);
    const uint4 u0 = mrow[0], u1 = mrow[1], u2 = mrow[2];
    unsigned in[12] = {u0.x, u0.y, u0.z, u0.w, u1.x, u1.y, u1.z, u1.w, u2.x, u2.y, u2.z, u2.w};
    unsigned ow[12];
    #pragma unroll
    for (int c2 = 0; c2 < 12; ++c2) ow[c2] = pk2(g * bflo(in[c2]), g * bfhi(in[c2]));
    char* slot = gmbuf + (size_t)posl[e] * SLOT;
    *(uint4*)(slot + q * 48 + 0)  = make_uint4(ow[0], ow[1], ow[2], ow[3]);
    *(uint4*)(slot + q * 48 + 16) = make_uint4(ow[4], ow[5], ow[6], ow[7]);
    *(uint4*)(slot + q * 48 + 32) = make_uint4(ow[8], ow[9], ow[10], ow[11]);
    if (q == 0) { phiv[posl[e]] = phil[e]; vjv[posl[e]] = vjl[e]; }
  }
}

// ---------------------------------------------------------------------------
// kred: one wave per node; sum its contiguous slot run
__global__ __launch_bounds__(256, 8) void kred(const float* __restrict__ x,
    const char* __restrict__ gmbuf, const int* __restrict__ base,
    const float* __restrict__ phiv, const int* __restrict__ vjv,
    float* __restrict__ wm, float* __restrict__ svm) {
  const int t = threadIdx.x, l = t & 63;
  const int node = blockIdx.x * 4 + (t >> 6);
  const int b0 = base[node], b1 = base[node + 1];
  float a0 = 0.f, a1 = 0.f, sx = 0.f;
  for (int s = b0; s < b1; ++s) {
    const char* slot = gmbuf + (size_t)s * SLOT;
    if (l < 48) {
      const unsigned u = *(const unsigned*)(slot + l * 4);
      a0 += bflo(u); a1 += bfhi(u);
    } else if (l < 52) {
      sx = fmaf(phiv[s], x[(size_t)vjv[s] * 4 + (l - 48)], sx);
    }
  }
  if (l < 48) {
    *(float2*)(wm + (size_t)node * 96 + 2 * l) = make_float2(a0, a1);
  } else if (l < 52) {
    svm[(size_t)node * 4 + (l - 48)] = (b1 > b0) ? sx / (float)(b1 - b0) : 0.f;
  }
}

// ---------------------------------------------------------------------------
// K3a: tmp = relu([h, wm] @ Wh1 + bh1) — unchanged
__global__ __launch_bounds__(256, 3) void k3a_hidden(const float* __restrict__ h,
    const float* __restrict__ wmv, const float* __restrict__ Wh1,
    const float* __restrict__ bh1, float* __restrict__ tmp) {
  __shared__ float inT[192 * 64];
  const int tid = threadIdx.x, e = tid & 63, wq = tid >> 6;
  const int fb = rfl(wq * 24);
  const int node = blockIdx.x * 64 + e;
  const int nclamp = node < NN ? node : NN - 1;
  #pragma unroll
  for (int c = 0; c < 6; ++c) {
    const int k0 = fb + c * 4;
    const float4 v = *(const float4*)(h + (long)nclamp * 96 + k0);
    const float4 u = *(const float4*)(wmv + (long)nclamp * 96 + k0);
    inT[(k0 + 0) * 64 + e] = v.x; inT[(k0 + 1) * 64 + e] = v.y;
    inT[(k0 + 2) * 64 + e] = v.z; inT[(k0 + 3) * 64 + e] = v.w;
    inT[(96 + k0 + 0) * 64 + e] = u.x; inT[(96 + k0 + 1) * 64 + e] = u.y;
    inT[(96 + k0 + 2) * 64 + e] = u.z; inT[(96 + k0 + 3) * 64 + e] = u.w;
  }
  __syncthreads();
  float acc[24];
  #pragma unroll
  for (int t = 0; t < 24; ++t) acc[t] = bh1[fb + t];
  #pragma unroll 4
  for (int k = 0; k < 192; ++k) {
    const float a = inT[k * 64 + e];
    #pragma unroll
    for (int t = 0; t < 24; ++t) acc[t] = fmaf(a, Wh1[k * 96 + fb + t], acc[t]);
  }
  if (node < NN) {
    #pragma unroll
    for (int c = 0; c < 6; ++c)
      *(float4*)(tmp + (long)node * 96 + fb + c * 4) =
          make_float4(fmaxf(acc[c * 4], 0.f), fmaxf(acc[c * 4 + 1], 0.f),
                      fmaxf(acc[c * 4 + 2], 0.f), fmaxf(acc[c * 4 + 3], 0.f));
  }
}

// ---------------------------------------------------------------------------
// K3b: h_out = h + tmp @ Wh2 + bh2 ; x_out = x + C*mean — unchanged
__global__ __launch_bounds__(256, 6) void k3b_out(const float* __restrict__ h,
    const float* __restrict__ tmp, const float* __restrict__ Wh2,
    const float* __restrict__ bh2, const float* __restrict__ x,
    const float* __restrict__ svm,
    float* __restrict__ hout, float* __restrict__ xout) {
  __shared__ float inT[96 * 64];
  const int tid = threadIdx.x, e = tid & 63, wq = tid >> 6;
  const int fb = rfl(wq * 24);
  const int node = blockIdx.x * 64 + e;
  const int nclamp = node < NN ? node : NN - 1;
  #pragma unroll
  for (int c = 0; c < 6; ++c) {
    const int k0 = fb + c * 4;
    const float4 v = *(const float4*)(tmp + (long)nclamp * 96 + k0);
    inT[(k0 + 0) * 64 + e] = v.x; inT[(k0 + 1) * 64 + e] = v.y;
    inT[(k0 + 2) * 64 + e] = v.z; inT[(k0 + 3) * 64 + e] = v.w;
  }
  __syncthreads();
  float acc[24];
  #pragma unroll
  for (int t = 0; t < 24; ++t) acc[t] = bh2[fb + t];
  #pragma unroll 4
  for (int k = 0; k < 96; ++k) {
    const float a = inT[k * 64 + e];
    #pragma unroll
    for (int t = 0; t < 24; ++t) acc[t] = fmaf(a, Wh2[k * 96 + fb + t], acc[t]);
  }
  if (node < NN) {
    #pragma unroll
    for (int c = 0; c < 6; ++c) {
      const float4 hv = *(const float4*)(h + (long)node * 96 + fb + c * 4);
      *(float4*)(hout + (long)node * 96 + fb + c * 4) =
          make_float4(hv.x + acc[c * 4], hv.y + acc[c * 4 + 1],
                      hv.z + acc[c * 4 + 2], hv.w + acc[c * 4 + 3]);
    }
  }
  if (tid < 64 && node < NN) {
    const float4 s4 = *(const float4*)(svm + (long)node * 4);
    const float4 xv = *(const float4*)(x + (long)node * 4);
    *(float4*)(xout + (long)node * 4) =
        make_float4(xv.x + 0.005f * s4.x, xv.y + 0.005f * s4.y,
                    xv.z + 0.005f * s4.z, xv.w + 0.005f * s4.w);
  }
}

// ---------------------------------------------------------------------------
extern "C" void kernel_launch(void* const* d_in, const int* in_sizes, int n_in,
                              void* d_out, int out_size, void* d_ws, size_t ws_size,
                              hipStream_t stream) {
  const float* x   = (const float*)d_in[0];
  const float* h   = (const float*)d_in[1];
  const int*   ei  = (const int*)d_in[2];
  const int*   ej  = (const int*)d_in[3];
  const float* We1 = (const float*)d_in[4];
  const float* be1 = (const float*)d_in[5];
  const float* We2 = (const float*)d_in[6];
  const float* be2 = (const float*)d_in[7];
  const float* Wm  = (const float*)d_in[8];
  const float* bm  = (const float*)d_in[9];
  const float* Wh1 = (const float*)d_in[10];
  const float* bh1 = (const float*)d_in[11];
  const float* Wh2 = (const float*)d_in[12];
  const float* bh2 = (const float*)d_in[13];
  const float* Wx1 = (const float*)d_in[14];
  const float* bx1 = (const float*)d_in[15];
  const float* Wx2 = (const float*)d_in[16];

  char* w = (char*)d_ws;
  unsigned short* Abf  = (unsigned short*)w;                 //  9.6 MB
  unsigned short* Bbf  = (unsigned short*)(w + 9600000);     //  9.6 MB
  float* WMv  = (float*)(w + 19200000);                      // 19.2 MB
  float* SvM  = (float*)(w + 38400000);                      //  0.8 MB
  int*   cnt  = (int*)(w + 39200000);                        //  0.2 MB
  int*   base = (int*)(w + 39400000);                        //  0.2 MB (+4)
  int*   curs = (int*)(w + 39600064);                        //  0.2 MB
  unsigned short* We2p = (unsigned short*)(w + 39800064);    // 18 KB
  unsigned short* Wx1p = (unsigned short*)(w + 39818496);    // 18 KB
  char*  gmb  = w + 39836928;                                // 153.6 MB
  float* phiv = (float*)(w + 193436928);                     //  3.2 MB
  int*   vjv  = (int*)(w + 196636928);                       //  3.2 MB
  float* TMP  = (float*)w;                                   // alias Abf/Bbf after k1

  float* hout = (float*)d_out;
  float* xout = hout + 4800000;

  hipMemsetAsync(cnt, 0, NN * sizeof(int), stream);
  khist<<<NE / 256, 256, 0, stream>>>(ei, cnt);
  kscan<<<1, 1024, 0, stream>>>(cnt, base, curs);
  kwprep<<<36, 256, 0, stream>>>(We2, Wx1, We2p, Wx1p);
  k0_AB<<<782, 256, 0, stream>>>(h, We1, Abf, Bbf);
  k1_edge<<<NE / 64, 256, 0, stream>>>(x, Abf, Bbf, ei, ej, We1, be1, We2p, be2,
                                       Wm, bm, Wx1p, bx1, Wx2, curs, gmb, phiv, vjv);
  kred<<<NN / 4, 256, 0, stream>>>(x, gmb, base, phiv, vjv, WMv, SvM);
  k3a_hidden<<<782, 256, 0, stream>>>(h, WMv, Wh1, bh1, TMP);
  k3b_out<<<782, 256, 0, stream>>>(h, TMP, Wh2, bh2, x, SvM, hout, xout);
}

// Round 5
// 522.893 us; speedup vs baseline: 8.8586x; 1.1924x over previous
//
#include <hip/hip_runtime.h>
#include <math.h>

#define NN 50000
#define NE 800000

typedef __attribute__((ext_vector_type(8))) short short8v;
typedef __attribute__((ext_vector_type(4))) float f32x4;

__device__ __forceinline__ int rfl(int v) { return __builtin_amdgcn_readfirstlane(v); }
__device__ __forceinline__ unsigned short f2bf(float f) {
  unsigned u = __float_as_uint(f);
  u += 0x7FFFu + ((u >> 16) & 1u);
  return (unsigned short)(u >> 16);
}
__device__ __forceinline__ unsigned pk2(float a, float b) {
  return (unsigned)f2bf(a) | ((unsigned)f2bf(b) << 16);
}
__device__ __forceinline__ float bflo(unsigned u) { return __uint_as_float(u << 16); }
__device__ __forceinline__ float bfhi(unsigned u) { return __uint_as_float(u & 0xFFFF0000u); }

// ---------------------------------------------------------------------------
__global__ void khist(const int* __restrict__ ei, int* __restrict__ cnt) {
  const int i = blockIdx.x * 256 + threadIdx.x;
  atomicAdd(&cnt[ei[i]], 1);
}

__global__ void kscan(const int* __restrict__ cnt, int* __restrict__ base,
                      int* __restrict__ cursor) {
  __shared__ int ps[1024];
  const int t = threadIdx.x;
  const int st = t * 49;
  int s = 0;
  for (int i = 0; i < 49; ++i) { const int idx = st + i; s += (idx < NN) ? cnt[idx] : 0; }
  ps[t] = s;
  __syncthreads();
  for (int off = 1; off < 1024; off <<= 1) {
    const int v = (t >= off) ? ps[t - off] : 0;
    __syncthreads();
    ps[t] += v;
    __syncthreads();
  }
  int ex = (t == 0) ? 0 : ps[t - 1];
  for (int i = 0; i < 49; ++i) {
    const int idx = st + i;
    if (idx < NN) { base[idx] = ex; cursor[idx] = ex; ex += cnt[idx]; }
  }
  if (t == 1023) base[NN] = NE;
}

// sort edges by vi into (ei_s, ej_s) via cursor
__global__ void kperm(const int* __restrict__ ei, const int* __restrict__ ej,
                      int* __restrict__ cursor,
                      int* __restrict__ eis, int* __restrict__ ejs) {
  const int i = blockIdx.x * 256 + threadIdx.x;
  const int vi = ei[i];
  const int pos = atomicAdd(&cursor[vi], 1);
  eis[pos] = vi;
  ejs[pos] = ej[i];
}

// ---------------------------------------------------------------------------
// pack We2 / Wx1 into MFMA B-fragment-major bf16: frag idx = ((tk*6+tn)*64+lane)*8+j
__global__ void kwprep(const float* __restrict__ We2, const float* __restrict__ Wx1,
                       unsigned short* __restrict__ We2p, unsigned short* __restrict__ Wx1p) {
  const int t = blockIdx.x * 256 + threadIdx.x;   // 0..9215
  const int j = t & 7, lane = (t >> 3) & 63, tile = t >> 9;
  const int tk = tile / 6, tn = tile % 6;
  const int k = tk * 32 + (lane >> 4) * 8 + j;
  const int n = tn * 16 + (lane & 15);
  We2p[t] = f2bf(We2[k * 96 + n]);
  Wx1p[t] = f2bf(Wx1[k * 96 + n]);
}

// ---------------------------------------------------------------------------
// K0: A = h @ We1[0:96,:], B = h @ We1[96:192,:]  (bf16 outputs)
__global__ __launch_bounds__(256, 6) void k0_AB(const float* __restrict__ h,
                                                const float* __restrict__ We1,
                                                unsigned short* __restrict__ Abf,
                                                unsigned short* __restrict__ Bbf) {
  __shared__ float hT[96 * 64];
  const int tid = threadIdx.x, e = tid & 63, wq = tid >> 6;
  const int fb = rfl(wq * 24);
  const int node = blockIdx.x * 64 + e;
  const int nclamp = node < NN ? node : NN - 1;
  #pragma unroll
  for (int c = 0; c < 6; ++c) {
    const int k0 = fb + c * 4;
    const float4 v = *(const float4*)(h + (long)nclamp * 96 + k0);
    hT[(k0 + 0) * 64 + e] = v.x; hT[(k0 + 1) * 64 + e] = v.y;
    hT[(k0 + 2) * 64 + e] = v.z; hT[(k0 + 3) * 64 + e] = v.w;
  }
  __syncthreads();
  float acc[24];
  #pragma unroll
  for (int t = 0; t < 24; ++t) acc[t] = 0.f;
  #pragma unroll 4
  for (int k = 0; k < 96; ++k) {
    const float a = hT[k * 64 + e];
    #pragma unroll
    for (int t = 0; t < 24; ++t) acc[t] = fmaf(a, We1[k * 96 + fb + t], acc[t]);
  }
  if (node < NN) {
    unsigned* dst = (unsigned*)(Abf + (size_t)node * 96 + fb);
    #pragma unroll
    for (int p = 0; p < 12; ++p) dst[p] = pk2(acc[2 * p], acc[2 * p + 1]);
  }
  #pragma unroll
  for (int t = 0; t < 24; ++t) acc[t] = 0.f;
  #pragma unroll 4
  for (int k = 0; k < 96; ++k) {
    const float a = hT[k * 64 + e];
    #pragma unroll
    for (int t = 0; t < 24; ++t) acc[t] = fmaf(a, We1[(96 + k) * 96 + fb + t], acc[t]);
  }
  if (node < NN) {
    unsigned* dst = (unsigned*)(Bbf + (size_t)node * 96 + fb);
    #pragma unroll
    for (int p = 0; p < 12; ++p) dst[p] = pk2(acc[2 * p], acc[2 * p + 1]);
  }
}

// ---------------------------------------------------------------------------
// K1: per-edge MLPs via MFMA on SORTED edges + fused segmented reduction.
// 64 edges/block, 4 waves.
__global__ __launch_bounds__(256, 4) void k1_edge(const float* __restrict__ x,
    const unsigned short* __restrict__ Abf, const unsigned short* __restrict__ Bbf,
    const int* __restrict__ eis, const int* __restrict__ ejs,
    const float* __restrict__ We1, const float* __restrict__ be1,
    const unsigned short* __restrict__ We2p, const float* __restrict__ be2,
    const float* __restrict__ Wm, const float* __restrict__ bm,
    const unsigned short* __restrict__ Wx1p, const float* __restrict__ bx1,
    const float* __restrict__ Wx2,
    float* __restrict__ wmo, float* __restrict__ svo) {
  __shared__ unsigned short actT[64 * 104];  // [edge][feat] bf16, row stride 104
  __shared__ float gl[64];
  __shared__ float phil[64];
  __shared__ float xjl[64 * 4];
  __shared__ int vseq[66];                   // [0]=vprev, [1+e]=vi(e), [65]=vnext

  const int tid = threadIdx.x;
  const float bm0 = bm[0];
  const int tb = blockIdx.x * 64;

  // ---- phase 0: gather + h1
  {
    const int e2 = tid & 63, fb = (tid >> 6) * 24;
    const int vi = eis[tb + e2], vj = ejs[tb + e2];
    const float4 xi = *(const float4*)(x + (long)vi * 4);
    const float4 xj = *(const float4*)(x + (long)vj * 4);
    if (tid < 64) {
      vseq[1 + e2] = vi;
      xjl[e2 * 4 + 0] = xj.x; xjl[e2 * 4 + 1] = xj.y;
      xjl[e2 * 4 + 2] = xj.z; xjl[e2 * 4 + 3] = xj.w;
    }
    if (tid == 0) {
      vseq[0]  = (tb > 0) ? eis[tb - 1] : -1;
      vseq[65] = (tb + 64 < NE) ? eis[tb + 64] : -1;
    }
    const float d0 = xi.x - xj.x, d1 = xi.y - xj.y, d2 = xi.z - xj.z, d3 = xi.w - xj.w;
    const float nrm = d0 * d0 - d1 * d1 - d2 * d2 - d3 * d3;
    const float prd = xi.x * xj.x - xi.y * xj.y - xi.z * xj.z - xi.w * xj.w;
    const float pn = copysignf(logf(fabsf(nrm) + 1.f), nrm);
    const float pp = copysignf(logf(fabsf(prd) + 1.f), prd);
    const uint4* Ar = (const uint4*)(Abf + (size_t)vi * 96 + fb);
    const uint4* Br = (const uint4*)(Bbf + (size_t)vj * 96 + fb);
    const uint4 A0 = Ar[0], A1 = Ar[1], A2 = Ar[2];
    const uint4 B0 = Br[0], B1 = Br[1], B2 = Br[2];
    unsigned ua[12], ub[12];
    ua[0]=A0.x; ua[1]=A0.y; ua[2]=A0.z; ua[3]=A0.w; ua[4]=A1.x; ua[5]=A1.y;
    ua[6]=A1.z; ua[7]=A1.w; ua[8]=A2.x; ua[9]=A2.y; ua[10]=A2.z; ua[11]=A2.w;
    ub[0]=B0.x; ub[1]=B0.y; ub[2]=B0.z; ub[3]=B0.w; ub[4]=B1.x; ub[5]=B1.y;
    ub[6]=B1.z; ub[7]=B1.w; ub[8]=B2.x; ub[9]=B2.y; ub[10]=B2.z; ub[11]=B2.w;
    unsigned* arow = (unsigned*)actT + e2 * 52 + fb / 2;
    #pragma unroll
    for (int p = 0; p < 12; ++p) {
      const int f = fb + 2 * p;
      const float lo = fmaxf(bflo(ua[p]) + bflo(ub[p]) + pn * We1[192 * 96 + f] + pp * We1[193 * 96 + f] + be1[f], 0.f);
      const float hi = fmaxf(bfhi(ua[p]) + bfhi(ub[p]) + pn * We1[192 * 96 + f + 1] + pp * We1[193 * 96 + f + 1] + be1[f + 1], 0.f);
      arow[p] = pk2(lo, hi);
    }
  }
  __syncthreads();

  const int l = tid & 63, w = tid >> 6;
  const int cg = l & 15, rg = l >> 4;
  const short8v* Wp2 = (const short8v*)We2p;
  const short8v* Wpx = (const short8v*)Wx1p;

  // ---- GEMM2: m = relu(h1 @ We2 + be2); gate partials
  {
    const unsigned short* ar = actT + (w * 16 + cg) * 104;
    const short8v af0 = *(const short8v*)(ar + rg * 8);
    const short8v af1 = *(const short8v*)(ar + 32 + rg * 8);
    const short8v af2 = *(const short8v*)(ar + 64 + rg * 8);
    f32x4 acc[6];
    #pragma unroll
    for (int tn = 0; tn < 6; ++tn) acc[tn] = (f32x4){0.f, 0.f, 0.f, 0.f};
    #pragma unroll
    for (int tn = 0; tn < 6; ++tn) {
      acc[tn] = __builtin_amdgcn_mfma_f32_16x16x32_bf16(af0, Wp2[(0 * 6 + tn) * 64 + l], acc[tn], 0, 0, 0);
      acc[tn] = __builtin_amdgcn_mfma_f32_16x16x32_bf16(af1, Wp2[(1 * 6 + tn) * 64 + l], acc[tn], 0, 0, 0);
      acc[tn] = __builtin_amdgcn_mfma_f32_16x16x32_bf16(af2, Wp2[(2 * 6 + tn) * 64 + l], acc[tn], 0, 0, 0);
    }
    float gp[4] = {0.f, 0.f, 0.f, 0.f};
    #pragma unroll
    for (int tn = 0; tn < 6; ++tn) {
      const int col = tn * 16 + cg;
      const float b = be2[col], wmw = Wm[col];
      #pragma unroll
      for (int r = 0; r < 4; ++r) {
        const float v = fmaxf(acc[tn][r] + b, 0.f);
        gp[r] = fmaf(v, wmw, gp[r]);
        actT[(w * 16 + rg * 4 + r) * 104 + col] = (short)f2bf(v);
      }
    }
    #pragma unroll
    for (int r = 0; r < 4; ++r) {
      float s = gp[r];
      s += __shfl_xor(s, 1); s += __shfl_xor(s, 2);
      s += __shfl_xor(s, 4); s += __shfl_xor(s, 8);
      if (cg == 0) gl[w * 16 + rg * 4 + r] = 1.f / (1.f + expf(-(s + bm0)));
    }
  }
  __syncthreads();

  // ---- GEMM3: phi = relu(m @ Wx1 + bx1) . Wx2
  {
    const unsigned short* mr = actT + (w * 16 + cg) * 104;
    const short8v mf0 = *(const short8v*)(mr + rg * 8);
    const short8v mf1 = *(const short8v*)(mr + 32 + rg * 8);
    const short8v mf2 = *(const short8v*)(mr + 64 + rg * 8);
    f32x4 acc[6];
    #pragma unroll
    for (int tn = 0; tn < 6; ++tn) acc[tn] = (f32x4){0.f, 0.f, 0.f, 0.f};
    #pragma unroll
    for (int tn = 0; tn < 6; ++tn) {
      acc[tn] = __builtin_amdgcn_mfma_f32_16x16x32_bf16(mf0, Wpx[(0 * 6 + tn) * 64 + l], acc[tn], 0, 0, 0);
      acc[tn] = __builtin_amdgcn_mfma_f32_16x16x32_bf16(mf1, Wpx[(1 * 6 + tn) * 64 + l], acc[tn], 0, 0, 0);
      acc[tn] = __builtin_amdgcn_mfma_f32_16x16x32_bf16(mf2, Wpx[(2 * 6 + tn) * 64 + l], acc[tn], 0, 0, 0);
    }
    float pp2[4] = {0.f, 0.f, 0.f, 0.f};
    #pragma unroll
    for (int tn = 0; tn < 6; ++tn) {
      const int col = tn * 16 + cg;
      const float b = bx1[col], wxw = Wx2[col];
      #pragma unroll
      for (int r = 0; r < 4; ++r)
        pp2[r] = fmaf(fmaxf(acc[tn][r] + b, 0.f), wxw, pp2[r]);
    }
    #pragma unroll
    for (int r = 0; r < 4; ++r) {
      float s = pp2[r];
      s += __shfl_xor(s, 1); s += __shfl_xor(s, 2);
      s += __shfl_xor(s, 4); s += __shfl_xor(s, 8);
      if (cg == 0) phil[w * 16 + rg * 4 + r] = s;
    }
  }
  __syncthreads();

  // ---- fused segmented reduction over the sorted 64-edge tile
  // threads 0..95: wm columns; 96..99: x components. Flush at run ends.
  if (tid < 100) {
    const int col = tid;
    float acc = 0.f;
    int start = 0;
    for (int e = 0; e < 64; ++e) {
      float val;
      if (col < 96)
        val = gl[e] * __uint_as_float(((unsigned)actT[e * 104 + col]) << 16);
      else
        val = phil[e] * xjl[e * 4 + (col - 96)];
      acc += val;
      const bool endrun = (e == 63) || (vseq[e + 1] != vseq[e + 2]);
      if (endrun) {
        const int node = vseq[e + 1];
        const bool cl = (start > 0) || (vseq[0] != vseq[1]);
        const bool cr = (e < 63) || (vseq[64] != vseq[65]);
        if (col < 96) {
          float* dst = wmo + (size_t)node * 96 + col;
          if (cl && cr) *dst = acc; else atomicAdd(dst, acc);
        } else {
          float* dst = svo + (size_t)node * 4 + (col - 96);
          if (cl && cr) *dst = acc; else atomicAdd(dst, acc);
        }
        acc = 0.f; start = e + 1;
      }
    }
  }
}

// ---------------------------------------------------------------------------
// K3a: tmp = relu([h, wm] @ Wh1 + bh1)
__global__ __launch_bounds__(256, 3) void k3a_hidden(const float* __restrict__ h,
    const float* __restrict__ wmv, const float* __restrict__ Wh1,
    const float* __restrict__ bh1, float* __restrict__ tmp) {
  __shared__ float inT[192 * 64];
  const int tid = threadIdx.x, e = tid & 63, wq = tid >> 6;
  const int fb = rfl(wq * 24);
  const int node = blockIdx.x * 64 + e;
  const int nclamp = node < NN ? node : NN - 1;
  #pragma unroll
  for (int c = 0; c < 6; ++c) {
    const int k0 = fb + c * 4;
    const float4 v = *(const float4*)(h + (long)nclamp * 96 + k0);
    const float4 u = *(const float4*)(wmv + (long)nclamp * 96 + k0);
    inT[(k0 + 0) * 64 + e] = v.x; inT[(k0 + 1) * 64 + e] = v.y;
    inT[(k0 + 2) * 64 + e] = v.z; inT[(k0 + 3) * 64 + e] = v.w;
    inT[(96 + k0 + 0) * 64 + e] = u.x; inT[(96 + k0 + 1) * 64 + e] = u.y;
    inT[(96 + k0 + 2) * 64 + e] = u.z; inT[(96 + k0 + 3) * 64 + e] = u.w;
  }
  __syncthreads();
  float acc[24];
  #pragma unroll
  for (int t = 0; t < 24; ++t) acc[t] = bh1[fb + t];
  #pragma unroll 4
  for (int k = 0; k < 192; ++k) {
    const float a = inT[k * 64 + e];
    #pragma unroll
    for (int t = 0; t < 24; ++t) acc[t] = fmaf(a, Wh1[k * 96 + fb + t], acc[t]);
  }
  if (node < NN) {
    #pragma unroll
    for (int c = 0; c < 6; ++c)
      *(float4*)(tmp + (long)node * 96 + fb + c * 4) =
          make_float4(fmaxf(acc[c * 4], 0.f), fmaxf(acc[c * 4 + 1], 0.f),
                      fmaxf(acc[c * 4 + 2], 0.f), fmaxf(acc[c * 4 + 3], 0.f));
  }
}

// ---------------------------------------------------------------------------
// K3b: h_out = h + tmp @ Wh2 + bh2 ; x_out = x + C*mean  (mean = sum/cnt via base)
__global__ __launch_bounds__(256, 6) void k3b_out(const float* __restrict__ h,
    const float* __restrict__ tmp, const float* __restrict__ Wh2,
    const float* __restrict__ bh2, const float* __restrict__ x,
    const float* __restrict__ svm, const int* __restrict__ base,
    float* __restrict__ hout, float* __restrict__ xout) {
  __shared__ float inT[96 * 64];
  const int tid = threadIdx.x, e = tid & 63, wq = tid >> 6;
  const int fb = rfl(wq * 24);
  const int node = blockIdx.x * 64 + e;
  const int nclamp = node < NN ? node : NN - 1;
  #pragma unroll
  for (int c = 0; c < 6; ++c) {
    const int k0 = fb + c * 4;
    const float4 v = *(const float4*)(tmp + (long)nclamp * 96 + k0);
    inT[(k0 + 0) * 64 + e] = v.x; inT[(k0 + 1) * 64 + e] = v.y;
    inT[(k0 + 2) * 64 + e] = v.z; inT[(k0 + 3) * 64 + e] = v.w;
  }
  __syncthreads();
  float acc[24];
  #pragma unroll
  for (int t = 0; t < 24; ++t) acc[t] = bh2[fb + t];
  #pragma unroll 4
  for (int k = 0; k < 96; ++k) {
    const float a = inT[k * 64 + e];
    #pragma unroll
    for (int t = 0; t < 24; ++t) acc[t] = fmaf(a, Wh2[k * 96 + fb + t], acc[t]);
  }
  if (node < NN) {
    #pragma unroll
    for (int c = 0; c < 6; ++c) {
      const float4 hv = *(const float4*)(h + (long)node * 96 + fb + c * 4);
      *(float4*)(hout + (long)node * 96 + fb + c * 4) =
          make_float4(hv.x + acc[c * 4], hv.y + acc[c * 4 + 1],
                      hv.z + acc[c * 4 + 2], hv.w + acc[c * 4 + 3]);
    }
  }
  if (tid < 64 && node < NN) {
    const int cnt = base[node + 1] - base[node];
    const float inv = cnt > 0 ? 1.f / (float)cnt : 0.f;
    const float4 s4 = *(const float4*)(svm + (long)node * 4);
    const float4 xv = *(const float4*)(x + (long)node * 4);
    *(float4*)(xout + (long)node * 4) =
        make_float4(xv.x + 0.005f * s4.x * inv, xv.y + 0.005f * s4.y * inv,
                    xv.z + 0.005f * s4.z * inv, xv.w + 0.005f * s4.w * inv);
  }
}

// ---------------------------------------------------------------------------
extern "C" void kernel_launch(void* const* d_in, const int* in_sizes, int n_in,
                              void* d_out, int out_size, void* d_ws, size_t ws_size,
                              hipStream_t stream) {
  const float* x   = (const float*)d_in[0];
  const float* h   = (const float*)d_in[1];
  const int*   ei  = (const int*)d_in[2];
  const int*   ej  = (const int*)d_in[3];
  const float* We1 = (const float*)d_in[4];
  const float* be1 = (const float*)d_in[5];
  const float* We2 = (const float*)d_in[6];
  const float* be2 = (const float*)d_in[7];
  const float* Wm  = (const float*)d_in[8];
  const float* bm  = (const float*)d_in[9];
  const float* Wh1 = (const float*)d_in[10];
  const float* bh1 = (const float*)d_in[11];
  const float* Wh2 = (const float*)d_in[12];
  const float* bh2 = (const float*)d_in[13];
  const float* Wx1 = (const float*)d_in[14];
  const float* bx1 = (const float*)d_in[15];
  const float* Wx2 = (const float*)d_in[16];

  char* w = (char*)d_ws;
  unsigned short* Abf  = (unsigned short*)w;                 //  9.6 MB
  unsigned short* Bbf  = (unsigned short*)(w + 9600000);     //  9.6 MB
  float* WMv  = (float*)(w + 19200000);                      // 19.2 MB
  float* SvM  = (float*)(w + 38400000);                      //  0.8 MB
  int*   cnt  = (int*)(w + 39200000);                        //  0.2 MB
  int*   base = (int*)(w + 39400000);                        //  0.2 MB (+4)
  int*   curs = (int*)(w + 39600064);                        //  0.2 MB
  unsigned short* We2p = (unsigned short*)(w + 39800064);    // 18 KB
  unsigned short* Wx1p = (unsigned short*)(w + 39818496);    // 18 KB
  int*   eis  = (int*)(w + 39836928);                        //  3.2 MB
  int*   ejs  = (int*)(w + 43036928);                        //  3.2 MB
  float* TMP  = (float*)w;                                   // alias Abf/Bbf after k1

  float* hout = (float*)d_out;
  float* xout = hout + 4800000;

  hipMemsetAsync(cnt, 0, NN * sizeof(int), stream);
  hipMemsetAsync(WMv, 0, (size_t)(4800000 + 200000) * sizeof(float), stream);
  khist<<<NE / 256, 256, 0, stream>>>(ei, cnt);
  kscan<<<1, 1024, 0, stream>>>(cnt, base, curs);
  kperm<<<NE / 256, 256, 0, stream>>>(ei, ej, curs, eis, ejs);
  kwprep<<<36, 256, 0, stream>>>(We2, Wx1, We2p, Wx1p);
  k0_AB<<<782, 256, 0, stream>>>(h, We1, Abf, Bbf);
  k1_edge<<<NE / 64, 256, 0, stream>>>(x, Abf, Bbf, eis, ejs, We1, be1, We2p, be2,
                                       Wm, bm, Wx1p, bx1, Wx2, WMv, SvM);
  k3a_hidden<<<782, 256, 0, stream>>>(h, WMv, Wh1, bh1, TMP);
  k3b_out<<<782, 256, 0, stream>>>(h, TMP, Wh2, bh2, x, SvM, base, hout, xout);
}

// Round 6
// 438.192 us; speedup vs baseline: 10.5709x; 1.1933x over previous
//
#include <hip/hip_runtime.h>
#include <math.h>

#define NN 50000
#define NE 800000

typedef __attribute__((ext_vector_type(8))) short short8v;
typedef __attribute__((ext_vector_type(4))) float f32x4;

__device__ __forceinline__ int rfl(int v) { return __builtin_amdgcn_readfirstlane(v); }
__device__ __forceinline__ unsigned short f2bf(float f) {
  unsigned u = __float_as_uint(f);
  u += 0x7FFFu + ((u >> 16) & 1u);
  return (unsigned short)(u >> 16);
}
__device__ __forceinline__ unsigned pk2(float a, float b) {
  return (unsigned)f2bf(a) | ((unsigned)f2bf(b) << 16);
}
__device__ __forceinline__ float bflo(unsigned u) { return __uint_as_float(u << 16); }
__device__ __forceinline__ float bfhi(unsigned u) { return __uint_as_float(u & 0xFFFF0000u); }

// ---------------------------------------------------------------------------
__global__ void khist(const int* __restrict__ ei, int* __restrict__ cnt) {
  const int i = blockIdx.x * 256 + threadIdx.x;
  atomicAdd(&cnt[ei[i]], 1);
}

__global__ void kscan(const int* __restrict__ cnt, int* __restrict__ base,
                      int* __restrict__ cursor) {
  __shared__ int ps[1024];
  const int t = threadIdx.x;
  const int st = t * 49;
  int s = 0;
  for (int i = 0; i < 49; ++i) { const int idx = st + i; s += (idx < NN) ? cnt[idx] : 0; }
  ps[t] = s;
  __syncthreads();
  for (int off = 1; off < 1024; off <<= 1) {
    const int v = (t >= off) ? ps[t - off] : 0;
    __syncthreads();
    ps[t] += v;
    __syncthreads();
  }
  int ex = (t == 0) ? 0 : ps[t - 1];
  for (int i = 0; i < 49; ++i) {
    const int idx = st + i;
    if (idx < NN) { base[idx] = ex; cursor[idx] = ex; ex += cnt[idx]; }
  }
  if (t == 1023) base[NN] = NE;
}

__global__ void kperm(const int* __restrict__ ei, const int* __restrict__ ej,
                      int* __restrict__ cursor,
                      int* __restrict__ eis, int* __restrict__ ejs) {
  const int i = blockIdx.x * 256 + threadIdx.x;
  const int vi = ei[i];
  const int pos = atomicAdd(&cursor[vi], 1);
  eis[pos] = vi;
  ejs[pos] = ej[i];
}

// ---------------------------------------------------------------------------
// pack all weights into MFMA B-fragment-major bf16:
// for a KxN weight: tile (tk,tn); idx=((tk*NT+tn)*64+lane)*8+j; k=tk*32+(lane>>4)*8+j; n=tn*16+(lane&15)
__global__ void kwprep(const float* __restrict__ We1, const float* __restrict__ We2,
                       const float* __restrict__ Wx1, const float* __restrict__ Wh1,
                       const float* __restrict__ Wh2,
                       unsigned short* __restrict__ We1p, unsigned short* __restrict__ We2p,
                       unsigned short* __restrict__ Wx1p, unsigned short* __restrict__ Wh1p,
                       unsigned short* __restrict__ Wh2p) {
  const int t = blockIdx.x * 256 + threadIdx.x;   // 0..18431
  const int j = t & 7, lane = (t >> 3) & 63;
  const int kk = (lane >> 4) * 8 + j;
  const int nn = lane & 15;
  {  // We1p: K=96, N=192 (combined [top|bot])
    const int tile = t >> 9, tk = tile / 12, tn = tile % 12;
    const int k = tk * 32 + kk, n2 = tn * 16 + nn;
    const float v = (n2 < 96) ? We1[k * 96 + n2] : We1[(96 + k) * 96 + (n2 - 96)];
    We1p[t] = f2bf(v);
  }
  {  // Wh1p: K=192, N=96
    const int tile = t >> 9, tk = tile / 6, tn = tile % 6;
    const int k = tk * 32 + kk, n = tn * 16 + nn;
    Wh1p[t] = f2bf(Wh1[k * 96 + n]);
  }
  if (t < 9216) {  // We2p / Wx1p / Wh2p: K=96, N=96
    const int tile = t >> 9, tk = tile / 6, tn = tile % 6;
    const int k = tk * 32 + kk, n = tn * 16 + nn;
    We2p[t] = f2bf(We2[k * 96 + n]);
    Wx1p[t] = f2bf(Wx1[k * 96 + n]);
    Wh2p[t] = f2bf(Wh2[k * 96 + n]);
  }
}

// ---------------------------------------------------------------------------
// K0 (MFMA): [A|B] = h @ [We1_top | We1_bot], bf16 out. 64 nodes/block, 4 waves.
__global__ __launch_bounds__(256, 4) void k0_AB(const float* __restrict__ h,
                                                const unsigned short* __restrict__ We1p,
                                                unsigned short* __restrict__ Abf,
                                                unsigned short* __restrict__ Bbf) {
  __shared__ unsigned short hbT[64 * 104];   // [node][feat]
  __shared__ unsigned short outT[64 * 200];  // [node][0..191]
  const int tid = threadIdx.x;
  const int nb = blockIdx.x * 64;
  {
    const int e = tid & 63, q = tid >> 6;
    const int node = nb + e;
    const int nc = node < NN ? node : NN - 1;
    const float* hr = h + (long)nc * 96 + q * 24;
    unsigned* dst = (unsigned*)hbT + e * 52 + q * 12;
    #pragma unroll
    for (int c = 0; c < 6; ++c) {
      const float4 v = *(const float4*)(hr + c * 4);
      dst[c * 2]     = pk2(v.x, v.y);
      dst[c * 2 + 1] = pk2(v.z, v.w);
    }
  }
  __syncthreads();
  const int l = tid & 63, w = tid >> 6, cg = l & 15, rg = l >> 4;
  {
    const short8v* Wp = (const short8v*)We1p;
    const unsigned short* ar = hbT + (w * 16 + cg) * 104;
    const short8v af0 = *(const short8v*)(ar + rg * 8);
    const short8v af1 = *(const short8v*)(ar + 32 + rg * 8);
    const short8v af2 = *(const short8v*)(ar + 64 + rg * 8);
    #pragma unroll
    for (int tn = 0; tn < 12; ++tn) {
      f32x4 acc = (f32x4){0.f, 0.f, 0.f, 0.f};
      acc = __builtin_amdgcn_mfma_f32_16x16x32_bf16(af0, Wp[(0 * 12 + tn) * 64 + l], acc, 0, 0, 0);
      acc = __builtin_amdgcn_mfma_f32_16x16x32_bf16(af1, Wp[(1 * 12 + tn) * 64 + l], acc, 0, 0, 0);
      acc = __builtin_amdgcn_mfma_f32_16x16x32_bf16(af2, Wp[(2 * 12 + tn) * 64 + l], acc, 0, 0, 0);
      #pragma unroll
      for (int r = 0; r < 4; ++r)
        outT[(w * 16 + rg * 4 + r) * 200 + tn * 16 + cg] = f2bf(acc[r]);
    }
  }
  __syncthreads();
  {
    const int e = tid & 63, q = tid >> 6;
    const int node = nb + e;
    if (node < NN) {
      const unsigned* src = (const unsigned*)outT + e * 100;
      if (q < 2) {
        uint4* dA = (uint4*)(Abf + (size_t)node * 96);
        #pragma unroll
        for (int i = 0; i < 6; ++i) dA[q * 6 + i] = *(const uint4*)(src + (q * 6 + i) * 4);
      } else {
        uint4* dB = (uint4*)(Bbf + (size_t)node * 96);
        #pragma unroll
        for (int i = 0; i < 6; ++i) dB[(q - 2) * 6 + i] = *(const uint4*)(src + 48 + ((q - 2) * 6 + i) * 4);
      }
    }
  }
}

// ---------------------------------------------------------------------------
// K1: per-edge MLPs via MFMA on SORTED edges + fused segmented reduction.
__global__ __launch_bounds__(256, 4) void k1_edge(const float* __restrict__ x,
    const unsigned short* __restrict__ Abf, const unsigned short* __restrict__ Bbf,
    const int* __restrict__ eis, const int* __restrict__ ejs,
    const float* __restrict__ We1, const float* __restrict__ be1,
    const unsigned short* __restrict__ We2p, const float* __restrict__ be2,
    const float* __restrict__ Wm, const float* __restrict__ bm,
    const unsigned short* __restrict__ Wx1p, const float* __restrict__ bx1,
    const float* __restrict__ Wx2,
    float* __restrict__ wmo, float* __restrict__ svo) {
  __shared__ unsigned short actT[64 * 104];
  __shared__ float gl[64];
  __shared__ float phil[64];
  __shared__ float xjl[64 * 4];
  __shared__ int vseq[66];

  const int tid = threadIdx.x;
  const float bm0 = bm[0];
  const int tb = blockIdx.x * 64;

  {
    const int e2 = tid & 63, fb = (tid >> 6) * 24;
    const int vi = eis[tb + e2], vj = ejs[tb + e2];
    const float4 xi = *(const float4*)(x + (long)vi * 4);
    const float4 xj = *(const float4*)(x + (long)vj * 4);
    if (tid < 64) {
      vseq[1 + e2] = vi;
      xjl[e2 * 4 + 0] = xj.x; xjl[e2 * 4 + 1] = xj.y;
      xjl[e2 * 4 + 2] = xj.z; xjl[e2 * 4 + 3] = xj.w;
    }
    if (tid == 0) {
      vseq[0]  = (tb > 0) ? eis[tb - 1] : -1;
      vseq[65] = (tb + 64 < NE) ? eis[tb + 64] : -1;
    }
    const float d0 = xi.x - xj.x, d1 = xi.y - xj.y, d2 = xi.z - xj.z, d3 = xi.w - xj.w;
    const float nrm = d0 * d0 - d1 * d1 - d2 * d2 - d3 * d3;
    const float prd = xi.x * xj.x - xi.y * xj.y - xi.z * xj.z - xi.w * xj.w;
    const float pn = copysignf(logf(fabsf(nrm) + 1.f), nrm);
    const float pp = copysignf(logf(fabsf(prd) + 1.f), prd);
    const uint4* Ar = (const uint4*)(Abf + (size_t)vi * 96 + fb);
    const uint4* Br = (const uint4*)(Bbf + (size_t)vj * 96 + fb);
    const uint4 A0 = Ar[0], A1 = Ar[1], A2 = Ar[2];
    const uint4 B0 = Br[0], B1 = Br[1], B2 = Br[2];
    unsigned ua[12], ub[12];
    ua[0]=A0.x; ua[1]=A0.y; ua[2]=A0.z; ua[3]=A0.w; ua[4]=A1.x; ua[5]=A1.y;
    ua[6]=A1.z; ua[7]=A1.w; ua[8]=A2.x; ua[9]=A2.y; ua[10]=A2.z; ua[11]=A2.w;
    ub[0]=B0.x; ub[1]=B0.y; ub[2]=B0.z; ub[3]=B0.w; ub[4]=B1.x; ub[5]=B1.y;
    ub[6]=B1.z; ub[7]=B1.w; ub[8]=B2.x; ub[9]=B2.y; ub[10]=B2.z; ub[11]=B2.w;
    unsigned* arow = (unsigned*)actT + e2 * 52 + fb / 2;
    #pragma unroll
    for (int p = 0; p < 12; ++p) {
      const int f = fb + 2 * p;
      const float lo = fmaxf(bflo(ua[p]) + bflo(ub[p]) + pn * We1[192 * 96 + f] + pp * We1[193 * 96 + f] + be1[f], 0.f);
      const float hi = fmaxf(bfhi(ua[p]) + bfhi(ub[p]) + pn * We1[192 * 96 + f + 1] + pp * We1[193 * 96 + f + 1] + be1[f + 1], 0.f);
      arow[p] = pk2(lo, hi);
    }
  }
  __syncthreads();

  const int l = tid & 63, w = tid >> 6;
  const int cg = l & 15, rg = l >> 4;
  const short8v* Wp2 = (const short8v*)We2p;
  const short8v* Wpx = (const short8v*)Wx1p;

  {
    const unsigned short* ar = actT + (w * 16 + cg) * 104;
    const short8v af0 = *(const short8v*)(ar + rg * 8);
    const short8v af1 = *(const short8v*)(ar + 32 + rg * 8);
    const short8v af2 = *(const short8v*)(ar + 64 + rg * 8);
    f32x4 acc[6];
    #pragma unroll
    for (int tn = 0; tn < 6; ++tn) acc[tn] = (f32x4){0.f, 0.f, 0.f, 0.f};
    #pragma unroll
    for (int tn = 0; tn < 6; ++tn) {
      acc[tn] = __builtin_amdgcn_mfma_f32_16x16x32_bf16(af0, Wp2[(0 * 6 + tn) * 64 + l], acc[tn], 0, 0, 0);
      acc[tn] = __builtin_amdgcn_mfma_f32_16x16x32_bf16(af1, Wp2[(1 * 6 + tn) * 64 + l], acc[tn], 0, 0, 0);
      acc[tn] = __builtin_amdgcn_mfma_f32_16x16x32_bf16(af2, Wp2[(2 * 6 + tn) * 64 + l], acc[tn], 0, 0, 0);
    }
    float gp[4] = {0.f, 0.f, 0.f, 0.f};
    #pragma unroll
    for (int tn = 0; tn < 6; ++tn) {
      const int col = tn * 16 + cg;
      const float b = be2[col], wmw = Wm[col];
      #pragma unroll
      for (int r = 0; r < 4; ++r) {
        const float v = fmaxf(acc[tn][r] + b, 0.f);
        gp[r] = fmaf(v, wmw, gp[r]);
        actT[(w * 16 + rg * 4 + r) * 104 + col] = (short)f2bf(v);
      }
    }
    #pragma unroll
    for (int r = 0; r < 4; ++r) {
      float s = gp[r];
      s += __shfl_xor(s, 1); s += __shfl_xor(s, 2);
      s += __shfl_xor(s, 4); s += __shfl_xor(s, 8);
      if (cg == 0) gl[w * 16 + rg * 4 + r] = 1.f / (1.f + expf(-(s + bm0)));
    }
  }
  __syncthreads();

  {
    const unsigned short* mr = actT + (w * 16 + cg) * 104;
    const short8v mf0 = *(const short8v*)(mr + rg * 8);
    const short8v mf1 = *(const short8v*)(mr + 32 + rg * 8);
    const short8v mf2 = *(const short8v*)(mr + 64 + rg * 8);
    f32x4 acc[6];
    #pragma unroll
    for (int tn = 0; tn < 6; ++tn) acc[tn] = (f32x4){0.f, 0.f, 0.f, 0.f};
    #pragma unroll
    for (int tn = 0; tn < 6; ++tn) {
      acc[tn] = __builtin_amdgcn_mfma_f32_16x16x32_bf16(mf0, Wpx[(0 * 6 + tn) * 64 + l], acc[tn], 0, 0, 0);
      acc[tn] = __builtin_amdgcn_mfma_f32_16x16x32_bf16(mf1, Wpx[(1 * 6 + tn) * 64 + l], acc[tn], 0, 0, 0);
      acc[tn] = __builtin_amdgcn_mfma_f32_16x16x32_bf16(mf2, Wpx[(2 * 6 + tn) * 64 + l], acc[tn], 0, 0, 0);
    }
    float pp2[4] = {0.f, 0.f, 0.f, 0.f};
    #pragma unroll
    for (int tn = 0; tn < 6; ++tn) {
      const int col = tn * 16 + cg;
      const float b = bx1[col], wxw = Wx2[col];
      #pragma unroll
      for (int r = 0; r < 4; ++r)
        pp2[r] = fmaf(fmaxf(acc[tn][r] + b, 0.f), wxw, pp2[r]);
    }
    #pragma unroll
    for (int r = 0; r < 4; ++r) {
      float s = pp2[r];
      s += __shfl_xor(s, 1); s += __shfl_xor(s, 2);
      s += __shfl_xor(s, 4); s += __shfl_xor(s, 8);
      if (cg == 0) phil[w * 16 + rg * 4 + r] = s;
    }
  }
  __syncthreads();

  if (tid < 100) {
    const int col = tid;
    float acc = 0.f;
    int start = 0;
    for (int e = 0; e < 64; ++e) {
      float val;
      if (col < 96)
        val = gl[e] * __uint_as_float(((unsigned)actT[e * 104 + col]) << 16);
      else
        val = phil[e] * xjl[e * 4 + (col - 96)];
      acc += val;
      const bool endrun = (e == 63) || (vseq[e + 1] != vseq[e + 2]);
      if (endrun) {
        const int node = vseq[e + 1];
        const bool cl = (start > 0) || (vseq[0] != vseq[1]);
        const bool cr = (e < 63) || (vseq[64] != vseq[65]);
        if (col < 96) {
          float* dst = wmo + (size_t)node * 96 + col;
          if (cl && cr) *dst = acc; else atomicAdd(dst, acc);
        } else {
          float* dst = svo + (size_t)node * 4 + (col - 96);
          if (cl && cr) *dst = acc; else atomicAdd(dst, acc);
        }
        acc = 0.f; start = e + 1;
      }
    }
  }
}

// ---------------------------------------------------------------------------
// K3 fused (MFMA): tmp = relu([h,wm]@Wh1+bh1); h_out = h + tmp@Wh2 + bh2; x_out
__global__ __launch_bounds__(256, 4) void k3ab(const float* __restrict__ h,
    const float* __restrict__ wmv,
    const unsigned short* __restrict__ Wh1p, const float* __restrict__ bh1,
    const unsigned short* __restrict__ Wh2p, const float* __restrict__ bh2,
    const float* __restrict__ x, const float* __restrict__ svm,
    const int* __restrict__ basep,
    float* __restrict__ hout, float* __restrict__ xout) {
  __shared__ unsigned short inT[64 * 200];   // [node][0..191]
  __shared__ unsigned short tmpT[64 * 104];
  const int tid = threadIdx.x;
  const int nb = blockIdx.x * 64;
  {
    const int e = tid & 63, q = tid >> 6;
    const int node = nb + e;
    const int nc = node < NN ? node : NN - 1;
    const float* hr = h + (long)nc * 96 + q * 24;
    const float* wr = wmv + (long)nc * 96 + q * 24;
    unsigned* dh = (unsigned*)inT + e * 100 + q * 12;
    unsigned* dw = (unsigned*)inT + e * 100 + 48 + q * 12;
    #pragma unroll
    for (int c = 0; c < 6; ++c) {
      const float4 v = *(const float4*)(hr + c * 4);
      dh[c * 2]     = pk2(v.x, v.y);
      dh[c * 2 + 1] = pk2(v.z, v.w);
      const float4 u = *(const float4*)(wr + c * 4);
      dw[c * 2]     = pk2(u.x, u.y);
      dw[c * 2 + 1] = pk2(u.z, u.w);
    }
  }
  __syncthreads();
  const int l = tid & 63, w = tid >> 6, cg = l & 15, rg = l >> 4;
  {
    const unsigned short* ar = inT + (w * 16 + cg) * 200;
    short8v af[6];
    #pragma unroll
    for (int tk = 0; tk < 6; ++tk) af[tk] = *(const short8v*)(ar + tk * 32 + rg * 8);
    const short8v* Wp = (const short8v*)Wh1p;
    #pragma unroll
    for (int tn = 0; tn < 6; ++tn) {
      f32x4 acc = (f32x4){0.f, 0.f, 0.f, 0.f};
      #pragma unroll
      for (int tk = 0; tk < 6; ++tk)
        acc = __builtin_amdgcn_mfma_f32_16x16x32_bf16(af[tk], Wp[(tk * 6 + tn) * 64 + l], acc, 0, 0, 0);
      const int col = tn * 16 + cg;
      const float b = bh1[col];
      #pragma unroll
      for (int r = 0; r < 4; ++r)
        tmpT[(w * 16 + rg * 4 + r) * 104 + col] = f2bf(fmaxf(acc[r] + b, 0.f));
    }
  }
  __syncthreads();
  {
    const unsigned short* mr = tmpT + (w * 16 + cg) * 104;
    const short8v mf0 = *(const short8v*)(mr + rg * 8);
    const short8v mf1 = *(const short8v*)(mr + 32 + rg * 8);
    const short8v mf2 = *(const short8v*)(mr + 64 + rg * 8);
    const short8v* Wp = (const short8v*)Wh2p;
    #pragma unroll
    for (int tn = 0; tn < 6; ++tn) {
      f32x4 acc = (f32x4){0.f, 0.f, 0.f, 0.f};
      acc = __builtin_amdgcn_mfma_f32_16x16x32_bf16(mf0, Wp[(0 * 6 + tn) * 64 + l], acc, 0, 0, 0);
      acc = __builtin_amdgcn_mfma_f32_16x16x32_bf16(mf1, Wp[(1 * 6 + tn) * 64 + l], acc, 0, 0, 0);
      acc = __builtin_amdgcn_mfma_f32_16x16x32_bf16(mf2, Wp[(2 * 6 + tn) * 64 + l], acc, 0, 0, 0);
      const int col = tn * 16 + cg;
      const float b = bh2[col];
      #pragma unroll
      for (int r = 0; r < 4; ++r) {
        const int node = nb + w * 16 + rg * 4 + r;
        if (node < NN)
          hout[(size_t)node * 96 + col] = h[(size_t)node * 96 + col] + acc[r] + b;
      }
    }
  }
  if (tid < 64) {
    const int node = nb + tid;
    if (node < NN) {
      const int cnt = basep[node + 1] - basep[node];
      const float inv = cnt > 0 ? 1.f / (float)cnt : 0.f;
      const float4 s4 = *(const float4*)(svm + (long)node * 4);
      const float4 xv = *(const float4*)(x + (long)node * 4);
      *(float4*)(xout + (long)node * 4) =
          make_float4(xv.x + 0.005f * s4.x * inv, xv.y + 0.005f * s4.y * inv,
                      xv.z + 0.005f * s4.z * inv, xv.w + 0.005f * s4.w * inv);
    }
  }
}

// ---------------------------------------------------------------------------
extern "C" void kernel_launch(void* const* d_in, const int* in_sizes, int n_in,
                              void* d_out, int out_size, void* d_ws, size_t ws_size,
                              hipStream_t stream) {
  const float* x   = (const float*)d_in[0];
  const float* h   = (const float*)d_in[1];
  const int*   ei  = (const int*)d_in[2];
  const int*   ej  = (const int*)d_in[3];
  const float* We1 = (const float*)d_in[4];
  const float* be1 = (const float*)d_in[5];
  const float* We2 = (const float*)d_in[6];
  const float* be2 = (const float*)d_in[7];
  const float* Wm  = (const float*)d_in[8];
  const float* bm  = (const float*)d_in[9];
  const float* Wh1 = (const float*)d_in[10];
  const float* bh1 = (const float*)d_in[11];
  const float* Wh2 = (const float*)d_in[12];
  const float* bh2 = (const float*)d_in[13];
  const float* Wx1 = (const float*)d_in[14];
  const float* bx1 = (const float*)d_in[15];
  const float* Wx2 = (const float*)d_in[16];

  char* w = (char*)d_ws;
  unsigned short* Abf  = (unsigned short*)w;                 //  9.6 MB
  unsigned short* Bbf  = (unsigned short*)(w + 9600000);     //  9.6 MB
  float* WMv  = (float*)(w + 19200000);                      // 19.2 MB
  float* SvM  = (float*)(w + 38400000);                      //  0.8 MB
  int*   cnt  = (int*)(w + 39200000);                        //  0.2 MB
  int*   base = (int*)(w + 39400000);                        //  0.2 MB (+4)
  int*   curs = (int*)(w + 39600064);                        //  0.2 MB
  unsigned short* We2p = (unsigned short*)(w + 39800064);    // 18 KB
  unsigned short* Wx1p = (unsigned short*)(w + 39818496);    // 18 KB
  unsigned short* We1p = (unsigned short*)(w + 39836928);    // 36 KB
  unsigned short* Wh1p = (unsigned short*)(w + 39873792);    // 36 KB
  unsigned short* Wh2p = (unsigned short*)(w + 39910656);    // 18 KB
  int*   eis  = (int*)(w + 39929088);                        //  3.2 MB
  int*   ejs  = (int*)(w + 43129088);                        //  3.2 MB

  float* hout = (float*)d_out;
  float* xout = hout + 4800000;

  hipMemsetAsync(cnt, 0, NN * sizeof(int), stream);
  hipMemsetAsync(WMv, 0, (size_t)(4800000 + 200000) * sizeof(float), stream);
  khist<<<NE / 256, 256, 0, stream>>>(ei, cnt);
  kscan<<<1, 1024, 0, stream>>>(cnt, base, curs);
  kperm<<<NE / 256, 256, 0, stream>>>(ei, ej, curs, eis, ejs);
  kwprep<<<72, 256, 0, stream>>>(We1, We2, Wx1, Wh1, Wh2, We1p, We2p, Wx1p, Wh1p, Wh2p);
  k0_AB<<<782, 256, 0, stream>>>(h, We1p, Abf, Bbf);
  k1_edge<<<NE / 64, 256, 0, stream>>>(x, Abf, Bbf, eis, ejs, We1, be1, We2p, be2,
                                       Wm, bm, Wx1p, bx1, Wx2, WMv, SvM);
  k3ab<<<782, 256, 0, stream>>>(h, WMv, Wh1p, bh1, Wh2p, bh2, x, SvM, base, hout, xout);
}

// Round 7
// 316.261 us; speedup vs baseline: 14.6465x; 1.3855x over previous
//
#include <hip/hip_runtime.h>
#include <math.h>

#define NN 50000
#define NE 800000
#define NB 196   // scan blocks (196*256 >= NN)

typedef __attribute__((ext_vector_type(8))) short short8v;
typedef __attribute__((ext_vector_type(4))) float f32x4;

__device__ __forceinline__ int rfl(int v) { return __builtin_amdgcn_readfirstlane(v); }
__device__ __forceinline__ unsigned short f2bf(float f) {
  unsigned u = __float_as_uint(f);
  u += 0x7FFFu + ((u >> 16) & 1u);
  return (unsigned short)(u >> 16);
}
__device__ __forceinline__ unsigned pk2(float a, float b) {
  return (unsigned)f2bf(a) | ((unsigned)f2bf(b) << 16);
}
__device__ __forceinline__ float bflo(unsigned u) { return __uint_as_float(u << 16); }
__device__ __forceinline__ float bfhi(unsigned u) { return __uint_as_float(u & 0xFFFF0000u); }

// ---------------------------------------------------------------------------
__global__ void khist(const int* __restrict__ ei, int* __restrict__ cnt) {
  const int i = blockIdx.x * 256 + threadIdx.x;
  atomicAdd(&cnt[ei[i]], 1);
}

// multi-block exclusive scan: A) per-block local scan, B) block sums, C) add offsets
__global__ void kscanA(const int* __restrict__ cnt, int* __restrict__ pre,
                       int* __restrict__ bsum) {
  __shared__ int ps[256];
  const int b = blockIdx.x, t = threadIdx.x, idx = b * 256 + t;
  const int v = (idx < NN) ? cnt[idx] : 0;
  ps[t] = v;
  __syncthreads();
  for (int off = 1; off < 256; off <<= 1) {
    const int u = (t >= off) ? ps[t - off] : 0;
    __syncthreads();
    ps[t] += u;
    __syncthreads();
  }
  if (idx < NN) pre[idx] = ps[t] - v;
  if (t == 255) bsum[b] = ps[255];
}

__global__ void kscanB(const int* __restrict__ bsum, int* __restrict__ boff) {
  __shared__ int ps[256];
  const int t = threadIdx.x;
  const int v = (t < NB) ? bsum[t] : 0;
  ps[t] = v;
  __syncthreads();
  for (int off = 1; off < 256; off <<= 1) {
    const int u = (t >= off) ? ps[t - off] : 0;
    __syncthreads();
    ps[t] += u;
    __syncthreads();
  }
  if (t < NB) boff[t] = ps[t] - v;
}

__global__ void kscanC(const int* __restrict__ pre, const int* __restrict__ boff,
                       int* __restrict__ base, int* __restrict__ cursor) {
  const int b = blockIdx.x, t = threadIdx.x, idx = b * 256 + t;
  if (idx < NN) {
    const int v = pre[idx] + boff[b];
    base[idx] = v;
    cursor[idx] = v;
  }
  if (idx == 0) base[NN] = NE;
}

__global__ void kperm(const int* __restrict__ ei, const int* __restrict__ ej,
                      int* __restrict__ cursor,
                      int* __restrict__ eis, int* __restrict__ ejs) {
  const int i = blockIdx.x * 256 + threadIdx.x;
  const int vi = ei[i];
  const int pos = atomicAdd(&cursor[vi], 1);
  eis[pos] = vi;
  ejs[pos] = ej[i];
}

// ---------------------------------------------------------------------------
// pack all weights into MFMA B-fragment-major bf16
__global__ void kwprep(const float* __restrict__ We1, const float* __restrict__ We2,
                       const float* __restrict__ Wx1, const float* __restrict__ Wh1,
                       const float* __restrict__ Wh2,
                       unsigned short* __restrict__ We1p, unsigned short* __restrict__ We2p,
                       unsigned short* __restrict__ Wx1p, unsigned short* __restrict__ Wh1p,
                       unsigned short* __restrict__ Wh2p) {
  const int t = blockIdx.x * 256 + threadIdx.x;   // 0..18431
  const int j = t & 7, lane = (t >> 3) & 63;
  const int kk = (lane >> 4) * 8 + j;
  const int nn = lane & 15;
  {  // We1p: K=96, N=192 (combined [top|bot])
    const int tile = t >> 9, tk = tile / 12, tn = tile % 12;
    const int k = tk * 32 + kk, n2 = tn * 16 + nn;
    const float v = (n2 < 96) ? We1[k * 96 + n2] : We1[(96 + k) * 96 + (n2 - 96)];
    We1p[t] = f2bf(v);
  }
  {  // Wh1p: K=192, N=96
    const int tile = t >> 9, tk = tile / 6, tn = tile % 6;
    const int k = tk * 32 + kk, n = tn * 16 + nn;
    Wh1p[t] = f2bf(Wh1[k * 96 + n]);
  }
  if (t < 9216) {  // We2p / Wx1p / Wh2p: K=96, N=96
    const int tile = t >> 9, tk = tile / 6, tn = tile % 6;
    const int k = tk * 32 + kk, n = tn * 16 + nn;
    We2p[t] = f2bf(We2[k * 96 + n]);
    Wx1p[t] = f2bf(Wx1[k * 96 + n]);
    Wh2p[t] = f2bf(Wh2[k * 96 + n]);
  }
}

// ---------------------------------------------------------------------------
// K0 (MFMA): [A|B] = h @ [We1_top | We1_bot], bf16 out. 64 nodes/block, 4 waves.
__global__ __launch_bounds__(256, 4) void k0_AB(const float* __restrict__ h,
                                                const unsigned short* __restrict__ We1p,
                                                unsigned short* __restrict__ Abf,
                                                unsigned short* __restrict__ Bbf) {
  __shared__ __align__(16) unsigned short hbT[64 * 104];
  __shared__ __align__(16) unsigned short outT[64 * 200];
  const int tid = threadIdx.x;
  const int nb = blockIdx.x * 64;
  {
    const int e = tid & 63, q = tid >> 6;
    const int node = nb + e;
    const int nc = node < NN ? node : NN - 1;
    const float* hr = h + (long)nc * 96 + q * 24;
    unsigned* dst = (unsigned*)hbT + e * 52 + q * 12;
    #pragma unroll
    for (int c = 0; c < 6; ++c) {
      const float4 v = *(const float4*)(hr + c * 4);
      dst[c * 2]     = pk2(v.x, v.y);
      dst[c * 2 + 1] = pk2(v.z, v.w);
    }
  }
  __syncthreads();
  const int l = tid & 63, w = tid >> 6, cg = l & 15, rg = l >> 4;
  {
    const short8v* Wp = (const short8v*)We1p;
    const unsigned short* ar = hbT + (w * 16 + cg) * 104;
    const short8v af0 = *(const short8v*)(ar + rg * 8);
    const short8v af1 = *(const short8v*)(ar + 32 + rg * 8);
    const short8v af2 = *(const short8v*)(ar + 64 + rg * 8);
    #pragma unroll
    for (int tn = 0; tn < 12; ++tn) {
      f32x4 acc = (f32x4){0.f, 0.f, 0.f, 0.f};
      acc = __builtin_amdgcn_mfma_f32_16x16x32_bf16(af0, Wp[(0 * 12 + tn) * 64 + l], acc, 0, 0, 0);
      acc = __builtin_amdgcn_mfma_f32_16x16x32_bf16(af1, Wp[(1 * 12 + tn) * 64 + l], acc, 0, 0, 0);
      acc = __builtin_amdgcn_mfma_f32_16x16x32_bf16(af2, Wp[(2 * 12 + tn) * 64 + l], acc, 0, 0, 0);
      #pragma unroll
      for (int r = 0; r < 4; ++r)
        outT[(w * 16 + rg * 4 + r) * 200 + tn * 16 + cg] = f2bf(acc[r]);
    }
  }
  __syncthreads();
  {
    const int e = tid & 63, q = tid >> 6;
    const int node = nb + e;
    if (node < NN) {
      const unsigned* src = (const unsigned*)outT + e * 100;
      if (q < 2) {
        uint4* dA = (uint4*)(Abf + (size_t)node * 96);
        #pragma unroll
        for (int i = 0; i < 6; ++i) dA[q * 6 + i] = *(const uint4*)(src + (q * 6 + i) * 4);
      } else {
        uint4* dB = (uint4*)(Bbf + (size_t)node * 96);
        #pragma unroll
        for (int i = 0; i < 6; ++i) dB[(q - 2) * 6 + i] = *(const uint4*)(src + 48 + ((q - 2) * 6 + i) * 4);
      }
    }
  }
}

// ---------------------------------------------------------------------------
// K1: per-edge MLPs via MFMA on SORTED edges + fused segmented reduction.
__global__ __launch_bounds__(256, 8) void k1_edge(const float* __restrict__ x,
    const unsigned short* __restrict__ Abf, const unsigned short* __restrict__ Bbf,
    const int* __restrict__ eis, const int* __restrict__ ejs,
    const float* __restrict__ We1, const float* __restrict__ be1,
    const unsigned short* __restrict__ We2p, const float* __restrict__ be2,
    const float* __restrict__ Wm, const float* __restrict__ bm,
    const unsigned short* __restrict__ Wx1p, const float* __restrict__ bx1,
    const float* __restrict__ Wx2,
    float* __restrict__ wmo, float* __restrict__ svo) {
  __shared__ __align__(16) unsigned short actT[64 * 104];
  __shared__ float gl[64];
  __shared__ float phil[64];
  __shared__ float xjl[64 * 4];
  __shared__ int vseq[66];

  const int tid = threadIdx.x;
  const float bm0 = bm[0];
  const int tb = blockIdx.x * 64;

  {
    const int e2 = tid & 63, fb = (tid >> 6) * 24;
    const int vi = eis[tb + e2], vj = ejs[tb + e2];
    const float4 xi = *(const float4*)(x + (long)vi * 4);
    const float4 xj = *(const float4*)(x + (long)vj * 4);
    if (tid < 64) {
      vseq[1 + e2] = vi;
      xjl[e2 * 4 + 0] = xj.x; xjl[e2 * 4 + 1] = xj.y;
      xjl[e2 * 4 + 2] = xj.z; xjl[e2 * 4 + 3] = xj.w;
    }
    if (tid == 0) {
      vseq[0]  = (tb > 0) ? eis[tb - 1] : -1;
      vseq[65] = (tb + 64 < NE) ? eis[tb + 64] : -1;
    }
    const float d0 = xi.x - xj.x, d1 = xi.y - xj.y, d2 = xi.z - xj.z, d3 = xi.w - xj.w;
    const float nrm = d0 * d0 - d1 * d1 - d2 * d2 - d3 * d3;
    const float prd = xi.x * xj.x - xi.y * xj.y - xi.z * xj.z - xi.w * xj.w;
    const float pn = copysignf(logf(fabsf(nrm) + 1.f), nrm);
    const float pp = copysignf(logf(fabsf(prd) + 1.f), prd);
    const uint4* Ar = (const uint4*)(Abf + (size_t)vi * 96 + fb);
    const uint4* Br = (const uint4*)(Bbf + (size_t)vj * 96 + fb);
    const uint4 A0 = Ar[0], A1 = Ar[1], A2 = Ar[2];
    const uint4 B0 = Br[0], B1 = Br[1], B2 = Br[2];
    unsigned ua[12], ub[12];
    ua[0]=A0.x; ua[1]=A0.y; ua[2]=A0.z; ua[3]=A0.w; ua[4]=A1.x; ua[5]=A1.y;
    ua[6]=A1.z; ua[7]=A1.w; ua[8]=A2.x; ua[9]=A2.y; ua[10]=A2.z; ua[11]=A2.w;
    ub[0]=B0.x; ub[1]=B0.y; ub[2]=B0.z; ub[3]=B0.w; ub[4]=B1.x; ub[5]=B1.y;
    ub[6]=B1.z; ub[7]=B1.w; ub[8]=B2.x; ub[9]=B2.y; ub[10]=B2.z; ub[11]=B2.w;
    unsigned* arow = (unsigned*)actT + e2 * 52 + fb / 2;
    #pragma unroll
    for (int p = 0; p < 12; ++p) {
      const int f = fb + 2 * p;
      const float lo = fmaxf(bflo(ua[p]) + bflo(ub[p]) + pn * We1[192 * 96 + f] + pp * We1[193 * 96 + f] + be1[f], 0.f);
      const float hi = fmaxf(bfhi(ua[p]) + bfhi(ub[p]) + pn * We1[192 * 96 + f + 1] + pp * We1[193 * 96 + f + 1] + be1[f + 1], 0.f);
      arow[p] = pk2(lo, hi);
    }
  }
  __syncthreads();

  const int l = tid & 63, w = tid >> 6;
  const int cg = l & 15, rg = l >> 4;
  const short8v* Wp2 = (const short8v*)We2p;
  const short8v* Wpx = (const short8v*)Wx1p;

  {
    const unsigned short* ar = actT + (w * 16 + cg) * 104;
    const short8v af0 = *(const short8v*)(ar + rg * 8);
    const short8v af1 = *(const short8v*)(ar + 32 + rg * 8);
    const short8v af2 = *(const short8v*)(ar + 64 + rg * 8);
    f32x4 acc[6];
    #pragma unroll
    for (int tn = 0; tn < 6; ++tn) acc[tn] = (f32x4){0.f, 0.f, 0.f, 0.f};
    #pragma unroll
    for (int tn = 0; tn < 6; ++tn) {
      acc[tn] = __builtin_amdgcn_mfma_f32_16x16x32_bf16(af0, Wp2[(0 * 6 + tn) * 64 + l], acc[tn], 0, 0, 0);
      acc[tn] = __builtin_amdgcn_mfma_f32_16x16x32_bf16(af1, Wp2[(1 * 6 + tn) * 64 + l], acc[tn], 0, 0, 0);
      acc[tn] = __builtin_amdgcn_mfma_f32_16x16x32_bf16(af2, Wp2[(2 * 6 + tn) * 64 + l], acc[tn], 0, 0, 0);
    }
    float gp[4] = {0.f, 0.f, 0.f, 0.f};
    #pragma unroll
    for (int tn = 0; tn < 6; ++tn) {
      const int col = tn * 16 + cg;
      const float b = be2[col], wmw = Wm[col];
      #pragma unroll
      for (int r = 0; r < 4; ++r) {
        const float v = fmaxf(acc[tn][r] + b, 0.f);
        gp[r] = fmaf(v, wmw, gp[r]);
        actT[(w * 16 + rg * 4 + r) * 104 + col] = (short)f2bf(v);
      }
    }
    #pragma unroll
    for (int r = 0; r < 4; ++r) {
      float s = gp[r];
      s += __shfl_xor(s, 1); s += __shfl_xor(s, 2);
      s += __shfl_xor(s, 4); s += __shfl_xor(s, 8);
      if (cg == 0) gl[w * 16 + rg * 4 + r] = 1.f / (1.f + expf(-(s + bm0)));
    }
  }
  __syncthreads();

  {
    const unsigned short* mr = actT + (w * 16 + cg) * 104;
    const short8v mf0 = *(const short8v*)(mr + rg * 8);
    const short8v mf1 = *(const short8v*)(mr + 32 + rg * 8);
    const short8v mf2 = *(const short8v*)(mr + 64 + rg * 8);
    f32x4 acc[6];
    #pragma unroll
    for (int tn = 0; tn < 6; ++tn) acc[tn] = (f32x4){0.f, 0.f, 0.f, 0.f};
    #pragma unroll
    for (int tn = 0; tn < 6; ++tn) {
      acc[tn] = __builtin_amdgcn_mfma_f32_16x16x32_bf16(mf0, Wpx[(0 * 6 + tn) * 64 + l], acc[tn], 0, 0, 0);
      acc[tn] = __builtin_amdgcn_mfma_f32_16x16x32_bf16(mf1, Wpx[(1 * 6 + tn) * 64 + l], acc[tn], 0, 0, 0);
      acc[tn] = __builtin_amdgcn_mfma_f32_16x16x32_bf16(mf2, Wpx[(2 * 6 + tn) * 64 + l], acc[tn], 0, 0, 0);
    }
    float pp2[4] = {0.f, 0.f, 0.f, 0.f};
    #pragma unroll
    for (int tn = 0; tn < 6; ++tn) {
      const int col = tn * 16 + cg;
      const float b = bx1[col], wxw = Wx2[col];
      #pragma unroll
      for (int r = 0; r < 4; ++r)
        pp2[r] = fmaf(fmaxf(acc[tn][r] + b, 0.f), wxw, pp2[r]);
    }
    #pragma unroll
    for (int r = 0; r < 4; ++r) {
      float s = pp2[r];
      s += __shfl_xor(s, 1); s += __shfl_xor(s, 2);
      s += __shfl_xor(s, 4); s += __shfl_xor(s, 8);
      if (cg == 0) phil[w * 16 + rg * 4 + r] = s;
    }
  }
  __syncthreads();

  // ---- fused segmented reduction, split (col, half): 200 threads, 32 iters each
  if (tid < 200) {
    const bool isx = tid >= 192;
    const int col  = isx ? ((tid - 192) & 3) : (tid < 96 ? tid : tid - 96);
    const int half = isx ? ((tid - 192) >> 2) : (tid < 96 ? 0 : 1);
    const int s_lo = half * 32, s_hi = s_lo + 32;
    float acc = 0.f;
    bool clean = (vseq[s_lo] != vseq[s_lo + 1]);   // run starts exactly at s_lo
    for (int e = s_lo; e < s_hi; ++e) {
      float val;
      if (isx) val = phil[e] * xjl[e * 4 + col];
      else     val = gl[e] * __uint_as_float(((unsigned)actT[e * 104 + col]) << 16);
      acc += val;
      const bool gend = (vseq[e + 1] != vseq[e + 2]);   // run truly ends at e
      const bool last = (e == s_hi - 1);
      if (gend || last) {
        const int node = vseq[e + 1];
        float* dst = isx ? (svo + (size_t)node * 4 + col)
                         : (wmo + (size_t)node * 96 + col);
        if (clean && gend) *dst = acc; else atomicAdd(dst, acc);
        acc = 0.f; clean = true;
        if (last) break;
      }
    }
  }
}

// ---------------------------------------------------------------------------
// K3 fused (MFMA): tmp = relu([h,wm]@Wh1+bh1); h_out = h + tmp@Wh2 + bh2; x_out
__global__ __launch_bounds__(256, 4) void k3ab(const float* __restrict__ h,
    const float* __restrict__ wmv,
    const unsigned short* __restrict__ Wh1p, const float* __restrict__ bh1,
    const unsigned short* __restrict__ Wh2p, const float* __restrict__ bh2,
    const float* __restrict__ x, const float* __restrict__ svm,
    const int* __restrict__ basep,
    float* __restrict__ hout, float* __restrict__ xout) {
  __shared__ __align__(16) unsigned short inT[64 * 200];   // then reused as float[64][100]
  __shared__ __align__(16) unsigned short tmpT[64 * 104];
  const int tid = threadIdx.x;
  const int nb = blockIdx.x * 64;
  {
    const int e = tid & 63, q = tid >> 6;
    const int node = nb + e;
    const int nc = node < NN ? node : NN - 1;
    const float* hr = h + (long)nc * 96 + q * 24;
    const float* wr = wmv + (long)nc * 96 + q * 24;
    unsigned* dh = (unsigned*)inT + e * 100 + q * 12;
    unsigned* dw = (unsigned*)inT + e * 100 + 48 + q * 12;
    #pragma unroll
    for (int c = 0; c < 6; ++c) {
      const float4 v = *(const float4*)(hr + c * 4);
      dh[c * 2]     = pk2(v.x, v.y);
      dh[c * 2 + 1] = pk2(v.z, v.w);
      const float4 u = *(const float4*)(wr + c * 4);
      dw[c * 2]     = pk2(u.x, u.y);
      dw[c * 2 + 1] = pk2(u.z, u.w);
    }
  }
  __syncthreads();
  const int l = tid & 63, w = tid >> 6, cg = l & 15, rg = l >> 4;
  {
    const unsigned short* ar = inT + (w * 16 + cg) * 200;
    short8v af[6];
    #pragma unroll
    for (int tk = 0; tk < 6; ++tk) af[tk] = *(const short8v*)(ar + tk * 32 + rg * 8);
    const short8v* Wp = (const short8v*)Wh1p;
    #pragma unroll
    for (int tn = 0; tn < 6; ++tn) {
      f32x4 acc = (f32x4){0.f, 0.f, 0.f, 0.f};
      #pragma unroll
      for (int tk = 0; tk < 6; ++tk)
        acc = __builtin_amdgcn_mfma_f32_16x16x32_bf16(af[tk], Wp[(tk * 6 + tn) * 64 + l], acc, 0, 0, 0);
      const int col = tn * 16 + cg;
      const float b = bh1[col];
      #pragma unroll
      for (int r = 0; r < 4; ++r)
        tmpT[(w * 16 + rg * 4 + r) * 104 + col] = f2bf(fmaxf(acc[r] + b, 0.f));
    }
  }
  __syncthreads();
  {
    float* oT = (float*)inT;   // 64 x 100 floats (25.6 KB, inT no longer needed)
    const unsigned short* mr = tmpT + (w * 16 + cg) * 104;
    const short8v mf0 = *(const short8v*)(mr + rg * 8);
    const short8v mf1 = *(const short8v*)(mr + 32 + rg * 8);
    const short8v mf2 = *(const short8v*)(mr + 64 + rg * 8);
    const short8v* Wp = (const short8v*)Wh2p;
    #pragma unroll
    for (int tn = 0; tn < 6; ++tn) {
      f32x4 acc = (f32x4){0.f, 0.f, 0.f, 0.f};
      acc = __builtin_amdgcn_mfma_f32_16x16x32_bf16(mf0, Wp[(0 * 6 + tn) * 64 + l], acc, 0, 0, 0);
      acc = __builtin_amdgcn_mfma_f32_16x16x32_bf16(mf1, Wp[(1 * 6 + tn) * 64 + l], acc, 0, 0, 0);
      acc = __builtin_amdgcn_mfma_f32_16x16x32_bf16(mf2, Wp[(2 * 6 + tn) * 64 + l], acc, 0, 0, 0);
      const int col = tn * 16 + cg;
      const float b = bh2[col];
      #pragma unroll
      for (int r = 0; r < 4; ++r)
        oT[(w * 16 + rg * 4 + r) * 100 + col] = acc[r] + b;
    }
  }
  __syncthreads();
  {
    const int e = tid & 63, q = tid >> 6;
    const int node = nb + e;
    if (node < NN) {
      const float* src = (const float*)inT + e * 100 + q * 24;
      const float* hr = h + (size_t)node * 96 + q * 24;
      float* dst = hout + (size_t)node * 96 + q * 24;
      #pragma unroll
      for (int c = 0; c < 6; ++c) {
        const float4 s = *(const float4*)(src + c * 4);
        const float4 hv = *(const float4*)(hr + c * 4);
        *(float4*)(dst + c * 4) = make_float4(hv.x + s.x, hv.y + s.y, hv.z + s.z, hv.w + s.w);
      }
    }
  }
  if (tid < 64) {
    const int node = nb + tid;
    if (node < NN) {
      const int cnt = basep[node + 1] - basep[node];
      const float inv = cnt > 0 ? 1.f / (float)cnt : 0.f;
      const float4 s4 = *(const float4*)(svm + (long)node * 4);
      const float4 xv = *(const float4*)(x + (long)node * 4);
      *(float4*)(xout + (long)node * 4) =
          make_float4(xv.x + 0.005f * s4.x * inv, xv.y + 0.005f * s4.y * inv,
                      xv.z + 0.005f * s4.z * inv, xv.w + 0.005f * s4.w * inv);
    }
  }
}

// ---------------------------------------------------------------------------
extern "C" void kernel_launch(void* const* d_in, const int* in_sizes, int n_in,
                              void* d_out, int out_size, void* d_ws, size_t ws_size,
                              hipStream_t stream) {
  const float* x   = (const float*)d_in[0];
  const float* h   = (const float*)d_in[1];
  const int*   ei  = (const int*)d_in[2];
  const int*   ej  = (const int*)d_in[3];
  const float* We1 = (const float*)d_in[4];
  const float* be1 = (const float*)d_in[5];
  const float* We2 = (const float*)d_in[6];
  const float* be2 = (const float*)d_in[7];
  const float* Wm  = (const float*)d_in[8];
  const float* bm  = (const float*)d_in[9];
  const float* Wh1 = (const float*)d_in[10];
  const float* bh1 = (const float*)d_in[11];
  const float* Wh2 = (const float*)d_in[12];
  const float* bh2 = (const float*)d_in[13];
  const float* Wx1 = (const float*)d_in[14];
  const float* bx1 = (const float*)d_in[15];
  const float* Wx2 = (const float*)d_in[16];

  char* w = (char*)d_ws;
  unsigned short* Abf  = (unsigned short*)w;                 //  9.6 MB
  unsigned short* Bbf  = (unsigned short*)(w + 9600000);     //  9.6 MB
  float* WMv  = (float*)(w + 19200000);                      // 19.2 MB
  float* SvM  = (float*)(w + 38400000);                      //  0.8 MB
  int*   cnt  = (int*)(w + 39200000);                        //  0.2 MB
  int*   base = (int*)(w + 39400000);                        //  0.2 MB (+4)
  int*   curs = (int*)(w + 39600064);                        //  0.2 MB
  unsigned short* We2p = (unsigned short*)(w + 39800064);    // 18 KB
  unsigned short* Wx1p = (unsigned short*)(w + 39818496);    // 18 KB
  unsigned short* We1p = (unsigned short*)(w + 39836928);    // 36 KB
  unsigned short* Wh1p = (unsigned short*)(w + 39873792);    // 36 KB
  unsigned short* Wh2p = (unsigned short*)(w + 39910656);    // 18 KB
  int*   eis  = (int*)(w + 39929088);                        //  3.2 MB
  int*   ejs  = (int*)(w + 43129088);                        //  3.2 MB
  int*   pre  = (int*)(w + 46329088);                        //  0.2 MB
  int*   bsum = (int*)(w + 46529088);                        //  784 B
  int*   boff = (int*)(w + 46529872);                        //  784 B

  float* hout = (float*)d_out;
  float* xout = hout + 4800000;

  hipMemsetAsync(cnt, 0, NN * sizeof(int), stream);
  hipMemsetAsync(WMv, 0, (size_t)(4800000 + 200000) * sizeof(float), stream);
  khist<<<NE / 256, 256, 0, stream>>>(ei, cnt);
  kscanA<<<NB, 256, 0, stream>>>(cnt, pre, bsum);
  kscanB<<<1, 256, 0, stream>>>(bsum, boff);
  kscanC<<<NB, 256, 0, stream>>>(pre, boff, base, curs);
  kperm<<<NE / 256, 256, 0, stream>>>(ei, ej, curs, eis, ejs);
  kwprep<<<72, 256, 0, stream>>>(We1, We2, Wx1, Wh1, Wh2, We1p, We2p, Wx1p, Wh1p, Wh2p);
  k0_AB<<<782, 256, 0, stream>>>(h, We1p, Abf, Bbf);
  k1_edge<<<NE / 64, 256, 0, stream>>>(x, Abf, Bbf, eis, ejs, We1, be1, We2p, be2,
                                       Wm, bm, Wx1p, bx1, Wx2, WMv, SvM);
  k3ab<<<782, 256, 0, stream>>>(h, WMv, Wh1p, bh1, Wh2p, bh2, x, SvM, base, hout, xout);
}

// Round 8
// 312.739 us; speedup vs baseline: 14.8114x; 1.0113x over previous
//
#include <hip/hip_runtime.h>
#include <math.h>

#define NN 50000
#define NE 800000
#define NB 196   // scan blocks (196*256 >= NN)
#define TE 128   // edges per k1 block

typedef __attribute__((ext_vector_type(8))) short short8v;
typedef __attribute__((ext_vector_type(4))) float f32x4;

__device__ __forceinline__ int rfl(int v) { return __builtin_amdgcn_readfirstlane(v); }
__device__ __forceinline__ unsigned short f2bf(float f) {
  unsigned u = __float_as_uint(f);
  u += 0x7FFFu + ((u >> 16) & 1u);
  return (unsigned short)(u >> 16);
}
__device__ __forceinline__ unsigned pk2(float a, float b) {
  return (unsigned)f2bf(a) | ((unsigned)f2bf(b) << 16);
}
__device__ __forceinline__ float bflo(unsigned u) { return __uint_as_float(u << 16); }
__device__ __forceinline__ float bfhi(unsigned u) { return __uint_as_float(u & 0xFFFF0000u); }

// ---------------------------------------------------------------------------
__global__ void khist(const int* __restrict__ ei, int* __restrict__ cnt) {
  const int i = blockIdx.x * 256 + threadIdx.x;
  atomicAdd(&cnt[ei[i]], 1);
}

__global__ void kscanA(const int* __restrict__ cnt, int* __restrict__ pre,
                       int* __restrict__ bsum) {
  __shared__ int ps[256];
  const int b = blockIdx.x, t = threadIdx.x, idx = b * 256 + t;
  const int v = (idx < NN) ? cnt[idx] : 0;
  ps[t] = v;
  __syncthreads();
  for (int off = 1; off < 256; off <<= 1) {
    const int u = (t >= off) ? ps[t - off] : 0;
    __syncthreads();
    ps[t] += u;
    __syncthreads();
  }
  if (idx < NN) pre[idx] = ps[t] - v;
  if (t == 255) bsum[b] = ps[255];
}

__global__ void kscanB(const int* __restrict__ bsum, int* __restrict__ boff) {
  __shared__ int ps[256];
  const int t = threadIdx.x;
  const int v = (t < NB) ? bsum[t] : 0;
  ps[t] = v;
  __syncthreads();
  for (int off = 1; off < 256; off <<= 1) {
    const int u = (t >= off) ? ps[t - off] : 0;
    __syncthreads();
    ps[t] += u;
    __syncthreads();
  }
  if (t < NB) boff[t] = ps[t] - v;
}

__global__ void kscanC(const int* __restrict__ pre, const int* __restrict__ boff,
                       int* __restrict__ base, int* __restrict__ cursor) {
  const int b = blockIdx.x, t = threadIdx.x, idx = b * 256 + t;
  if (idx < NN) {
    const int v = pre[idx] + boff[b];
    base[idx] = v;
    cursor[idx] = v;
  }
  if (idx == 0) base[NN] = NE;
}

__global__ void kperm(const int* __restrict__ ei, const int* __restrict__ ej,
                      int* __restrict__ cursor,
                      int* __restrict__ eis, int* __restrict__ ejs) {
  const int i = blockIdx.x * 256 + threadIdx.x;
  const int vi = ei[i];
  const int pos = atomicAdd(&cursor[vi], 1);
  eis[pos] = vi;
  ejs[pos] = ej[i];
}

// ---------------------------------------------------------------------------
// pack all weights into MFMA B-fragment-major bf16
__global__ void kwprep(const float* __restrict__ We1, const float* __restrict__ We2,
                       const float* __restrict__ Wx1, const float* __restrict__ Wh1,
                       const float* __restrict__ Wh2,
                       unsigned short* __restrict__ We1p, unsigned short* __restrict__ We2p,
                       unsigned short* __restrict__ Wx1p, unsigned short* __restrict__ Wh1p,
                       unsigned short* __restrict__ Wh2p) {
  const int t = blockIdx.x * 256 + threadIdx.x;   // 0..18431
  const int j = t & 7, lane = (t >> 3) & 63;
  const int kk = (lane >> 4) * 8 + j;
  const int nn = lane & 15;
  {  // We1p: K=96, N=192 (combined [top|bot])
    const int tile = t >> 9, tk = tile / 12, tn = tile % 12;
    const int k = tk * 32 + kk, n2 = tn * 16 + nn;
    const float v = (n2 < 96) ? We1[k * 96 + n2] : We1[(96 + k) * 96 + (n2 - 96)];
    We1p[t] = f2bf(v);
  }
  {  // Wh1p: K=192, N=96
    const int tile = t >> 9, tk = tile / 6, tn = tile % 6;
    const int k = tk * 32 + kk, n = tn * 16 + nn;
    Wh1p[t] = f2bf(Wh1[k * 96 + n]);
  }
  if (t < 9216) {  // We2p / Wx1p / Wh2p: K=96, N=96
    const int tile = t >> 9, tk = tile / 6, tn = tile % 6;
    const int k = tk * 32 + kk, n = tn * 16 + nn;
    We2p[t] = f2bf(We2[k * 96 + n]);
    Wx1p[t] = f2bf(Wx1[k * 96 + n]);
    Wh2p[t] = f2bf(Wh2[k * 96 + n]);
  }
}

// ---------------------------------------------------------------------------
// K0 (MFMA): [A|B] = h @ [We1_top | We1_bot], bf16 out. 64 nodes/block, 4 waves.
__global__ __launch_bounds__(256, 4) void k0_AB(const float* __restrict__ h,
                                                const unsigned short* __restrict__ We1p,
                                                unsigned short* __restrict__ Abf,
                                                unsigned short* __restrict__ Bbf) {
  __shared__ __align__(16) unsigned short hbT[64 * 104];
  __shared__ __align__(16) unsigned short outT[64 * 200];
  const int tid = threadIdx.x;
  const int nb = blockIdx.x * 64;
  {
    const int e = tid & 63, q = tid >> 6;
    const int node = nb + e;
    const int nc = node < NN ? node : NN - 1;
    const float* hr = h + (long)nc * 96 + q * 24;
    unsigned* dst = (unsigned*)hbT + e * 52 + q * 12;
    #pragma unroll
    for (int c = 0; c < 6; ++c) {
      const float4 v = *(const float4*)(hr + c * 4);
      dst[c * 2]     = pk2(v.x, v.y);
      dst[c * 2 + 1] = pk2(v.z, v.w);
    }
  }
  __syncthreads();
  const int l = tid & 63, w = tid >> 6, cg = l & 15, rg = l >> 4;
  {
    const short8v* Wp = (const short8v*)We1p;
    const unsigned short* ar = hbT + (w * 16 + cg) * 104;
    const short8v af0 = *(const short8v*)(ar + rg * 8);
    const short8v af1 = *(const short8v*)(ar + 32 + rg * 8);
    const short8v af2 = *(const short8v*)(ar + 64 + rg * 8);
    #pragma unroll
    for (int tn = 0; tn < 12; ++tn) {
      f32x4 acc = (f32x4){0.f, 0.f, 0.f, 0.f};
      acc = __builtin_amdgcn_mfma_f32_16x16x32_bf16(af0, Wp[(0 * 12 + tn) * 64 + l], acc, 0, 0, 0);
      acc = __builtin_amdgcn_mfma_f32_16x16x32_bf16(af1, Wp[(1 * 12 + tn) * 64 + l], acc, 0, 0, 0);
      acc = __builtin_amdgcn_mfma_f32_16x16x32_bf16(af2, Wp[(2 * 12 + tn) * 64 + l], acc, 0, 0, 0);
      #pragma unroll
      for (int r = 0; r < 4; ++r)
        outT[(w * 16 + rg * 4 + r) * 200 + tn * 16 + cg] = f2bf(acc[r]);
    }
  }
  __syncthreads();
  {
    const int e = tid & 63, q = tid >> 6;
    const int node = nb + e;
    if (node < NN) {
      const unsigned* src = (const unsigned*)outT + e * 100;
      if (q < 2) {
        uint4* dA = (uint4*)(Abf + (size_t)node * 96);
        #pragma unroll
        for (int i = 0; i < 6; ++i) dA[q * 6 + i] = *(const uint4*)(src + (q * 6 + i) * 4);
      } else {
        uint4* dB = (uint4*)(Bbf + (size_t)node * 96);
        #pragma unroll
        for (int i = 0; i < 6; ++i) dB[(q - 2) * 6 + i] = *(const uint4*)(src + 48 + ((q - 2) * 6 + i) * 4);
      }
    }
  }
}

// ---------------------------------------------------------------------------
// K1: 128 sorted edges/block, 4 waves x 2 row-tiles; ballot run-mask reduction.
__global__ __launch_bounds__(256, 5) void k1_edge(const float* __restrict__ x,
    const unsigned short* __restrict__ Abf, const unsigned short* __restrict__ Bbf,
    const int* __restrict__ eis, const int* __restrict__ ejs,
    const float* __restrict__ We1, const float* __restrict__ be1,
    const unsigned short* __restrict__ We2p, const float* __restrict__ be2,
    const float* __restrict__ Wm, const float* __restrict__ bm,
    const unsigned short* __restrict__ Wx1p, const float* __restrict__ bx1,
    const float* __restrict__ Wx2,
    float* __restrict__ wmo, float* __restrict__ svo) {
  __shared__ __align__(16) unsigned short actT[TE * 104];
  __shared__ float gl[TE];
  __shared__ float phil[TE];
  __shared__ __align__(16) float xjl[TE * 4];
  __shared__ int vseq[TE + 2];
  __shared__ unsigned long long bmask[2];

  const int tid = threadIdx.x;
  const float bm0 = bm[0];
  const int tb = blockIdx.x * TE;

  // ---- phase 0: gather + h1 (thread: edge e2, feature half hf)
  {
    const int e2 = tid & 127, hf = tid >> 7;
    const int fb = hf * 48;
    const int vi = eis[tb + e2], vj = ejs[tb + e2];
    const float4 xi = *(const float4*)(x + (long)vi * 4);
    const float4 xj = *(const float4*)(x + (long)vj * 4);
    if (hf == 0) {
      vseq[1 + e2] = vi;
      *(float4*)(xjl + e2 * 4) = xj;
    }
    if (tid == 0) {
      vseq[0] = (tb > 0) ? eis[tb - 1] : -1;
      vseq[TE + 1] = (tb + TE < NE) ? eis[tb + TE] : -1;
    }
    const float d0 = xi.x - xj.x, d1 = xi.y - xj.y, d2 = xi.z - xj.z, d3 = xi.w - xj.w;
    const float nrm = d0 * d0 - d1 * d1 - d2 * d2 - d3 * d3;
    const float prd = xi.x * xj.x - xi.y * xj.y - xi.z * xj.z - xi.w * xj.w;
    const float pn = copysignf(logf(fabsf(nrm) + 1.f), nrm);
    const float pp = copysignf(logf(fabsf(prd) + 1.f), prd);
    const uint4* Ar = (const uint4*)(Abf + (size_t)vi * 96 + fb);
    const uint4* Br = (const uint4*)(Bbf + (size_t)vj * 96 + fb);
    const float* wA = We1 + 192 * 96 + fb;
    const float* wB = We1 + 193 * 96 + fb;
    const float* bE = be1 + fb;
    unsigned* arow = (unsigned*)actT + e2 * 52 + hf * 24;
    #pragma unroll
    for (int c = 0; c < 6; ++c) {
      const uint4 A4 = Ar[c], B4 = Br[c];
      const unsigned au[4] = {A4.x, A4.y, A4.z, A4.w};
      const unsigned bu[4] = {B4.x, B4.y, B4.z, B4.w};
      #pragma unroll
      for (int k2 = 0; k2 < 4; ++k2) {
        const int f = c * 8 + k2 * 2;
        const float lo = fmaxf(bflo(au[k2]) + bflo(bu[k2]) + pn * wA[f] + pp * wB[f] + bE[f], 0.f);
        const float hi = fmaxf(bfhi(au[k2]) + bfhi(bu[k2]) + pn * wA[f + 1] + pp * wB[f + 1] + bE[f + 1], 0.f);
        arow[c * 4 + k2] = pk2(lo, hi);
      }
    }
  }
  __syncthreads();

  // ---- run-end boundary mask via ballot (waves 0,1)
  if (tid < TE) {
    const int pred = (vseq[1 + tid] != vseq[2 + tid]) ? 1 : 0;
    const unsigned long long mk = __ballot(pred);
    if ((tid & 63) == 0) bmask[tid >> 6] = mk;
  }

  const int l = tid & 63, w = tid >> 6;
  const int cg = l & 15, rg = l >> 4;
  const int r0 = w * 32;
  const short8v* Wp2 = (const short8v*)We2p;
  const short8v* Wpx = (const short8v*)Wx1p;

  // ---- GEMM2: m = relu(h1 @ We2 + be2); gate
  {
    short8v af[2][3];
    #pragma unroll
    for (int rt = 0; rt < 2; ++rt)
      #pragma unroll
      for (int tk = 0; tk < 3; ++tk)
        af[rt][tk] = *(const short8v*)(actT + (r0 + rt * 16 + cg) * 104 + tk * 32 + rg * 8);
    f32x4 acc[2][6];
    #pragma unroll
    for (int rt = 0; rt < 2; ++rt)
      #pragma unroll
      for (int tn = 0; tn < 6; ++tn) acc[rt][tn] = (f32x4){0.f, 0.f, 0.f, 0.f};
    #pragma unroll
    for (int tk = 0; tk < 3; ++tk)
      #pragma unroll
      for (int tn = 0; tn < 6; ++tn) {
        const short8v bf = Wp2[(tk * 6 + tn) * 64 + l];
        acc[0][tn] = __builtin_amdgcn_mfma_f32_16x16x32_bf16(af[0][tk], bf, acc[0][tn], 0, 0, 0);
        acc[1][tn] = __builtin_amdgcn_mfma_f32_16x16x32_bf16(af[1][tk], bf, acc[1][tn], 0, 0, 0);
      }
    #pragma unroll
    for (int rt = 0; rt < 2; ++rt) {
      float gp[4] = {0.f, 0.f, 0.f, 0.f};
      #pragma unroll
      for (int tn = 0; tn < 6; ++tn) {
        const int col = tn * 16 + cg;
        const float b = be2[col], wmw = Wm[col];
        #pragma unroll
        for (int r = 0; r < 4; ++r) {
          const float v = fmaxf(acc[rt][tn][r] + b, 0.f);
          gp[r] = fmaf(v, wmw, gp[r]);
          actT[(r0 + rt * 16 + rg * 4 + r) * 104 + col] = (unsigned short)f2bf(v);
        }
      }
      #pragma unroll
      for (int r = 0; r < 4; ++r) {
        float s = gp[r];
        s += __shfl_xor(s, 1); s += __shfl_xor(s, 2);
        s += __shfl_xor(s, 4); s += __shfl_xor(s, 8);
        if (cg == 0) gl[r0 + rt * 16 + rg * 4 + r] = 1.f / (1.f + expf(-(s + bm0)));
      }
    }
  }

  // no barrier: each wave reads only its own rows (m written by itself)

  // ---- GEMM3: phi = relu(m @ Wx1 + bx1) . Wx2
  {
    short8v af[2][3];
    #pragma unroll
    for (int rt = 0; rt < 2; ++rt)
      #pragma unroll
      for (int tk = 0; tk < 3; ++tk)
        af[rt][tk] = *(const short8v*)(actT + (r0 + rt * 16 + cg) * 104 + tk * 32 + rg * 8);
    f32x4 acc[2][6];
    #pragma unroll
    for (int rt = 0; rt < 2; ++rt)
      #pragma unroll
      for (int tn = 0; tn < 6; ++tn) acc[rt][tn] = (f32x4){0.f, 0.f, 0.f, 0.f};
    #pragma unroll
    for (int tk = 0; tk < 3; ++tk)
      #pragma unroll
      for (int tn = 0; tn < 6; ++tn) {
        const short8v bf = Wpx[(tk * 6 + tn) * 64 + l];
        acc[0][tn] = __builtin_amdgcn_mfma_f32_16x16x32_bf16(af[0][tk], bf, acc[0][tn], 0, 0, 0);
        acc[1][tn] = __builtin_amdgcn_mfma_f32_16x16x32_bf16(af[1][tk], bf, acc[1][tn], 0, 0, 0);
      }
    #pragma unroll
    for (int rt = 0; rt < 2; ++rt) {
      float pp2[4] = {0.f, 0.f, 0.f, 0.f};
      #pragma unroll
      for (int tn = 0; tn < 6; ++tn) {
        const int col = tn * 16 + cg;
        const float b = bx1[col], wxw = Wx2[col];
        #pragma unroll
        for (int r = 0; r < 4; ++r)
          pp2[r] = fmaf(fmaxf(acc[rt][tn][r] + b, 0.f), wxw, pp2[r]);
      }
      #pragma unroll
      for (int r = 0; r < 4; ++r) {
        float s = pp2[r];
        s += __shfl_xor(s, 1); s += __shfl_xor(s, 2);
        s += __shfl_xor(s, 4); s += __shfl_xor(s, 8);
        if (cg == 0) phil[r0 + rt * 16 + rg * 4 + r] = s;
      }
    }
  }
  __syncthreads();

  // ---- fused segmented reduction via run-end bitmask
  if (tid < 192) {
    // wm: 96 cols x 4 quarters(32 edges); thread handles quarters q0 and q0+2
    const int q0 = (tid >= 96) ? 1 : 0;
    const int col = tid - 96 * q0;
    #pragma unroll
    for (int pass = 0; pass < 2; ++pass) {
      const int q = q0 + 2 * pass;
      const int s_lo = q * 32;
      const unsigned long long mk = bmask[s_lo >> 6];
      float acc2 = 0.f;
      bool clean = (q == 0) ? (vseq[0] != vseq[1])
                            : (((bmask[(s_lo - 1) >> 6] >> ((s_lo - 1) & 63)) & 1ull) != 0);
      for (int i = 0; i < 32; ++i) {
        const int e = s_lo + i;
        acc2 = fmaf(gl[e], __uint_as_float(((unsigned)actT[e * 104 + col]) << 16), acc2);
        const bool gend = ((mk >> (e & 63)) & 1ull) != 0;
        if (gend || i == 31) {
          const int node = vseq[e + 1];
          float* dst = wmo + (size_t)node * 96 + col;
          if (clean && gend) *dst = acc2; else atomicAdd(dst, acc2);
          acc2 = 0.f; clean = true;
        }
      }
    }
  } else if (tid < 224) {
    // x-part: 4 comps x 8 eighths(16 edges)
    const int t2 = tid - 192;
    const int comp = t2 & 3, q8 = t2 >> 2;
    const int s_lo = q8 * 16;
    const unsigned long long mk = bmask[s_lo >> 6];
    float acc2 = 0.f;
    bool clean = (q8 == 0) ? (vseq[0] != vseq[1])
                           : (((bmask[(s_lo - 1) >> 6] >> ((s_lo - 1) & 63)) & 1ull) != 0);
    for (int i = 0; i < 16; ++i) {
      const int e = s_lo + i;
      acc2 = fmaf(phil[e], xjl[e * 4 + comp], acc2);
      const bool gend = ((mk >> (e & 63)) & 1ull) != 0;
      if (gend || i == 15) {
        const int node = vseq[e + 1];
        float* dst = svo + (size_t)node * 4 + comp;
        if (clean && gend) *dst = acc2; else atomicAdd(dst, acc2);
        acc2 = 0.f; clean = true;
      }
    }
  }
}

// ---------------------------------------------------------------------------
// K3 fused (MFMA): tmp = relu([h,wm]@Wh1+bh1); h_out = h + tmp@Wh2 + bh2; x_out
__global__ __launch_bounds__(256, 4) void k3ab(const float* __restrict__ h,
    const float* __restrict__ wmv,
    const unsigned short* __restrict__ Wh1p, const float* __restrict__ bh1,
    const unsigned short* __restrict__ Wh2p, const float* __restrict__ bh2,
    const float* __restrict__ x, const float* __restrict__ svm,
    const int* __restrict__ basep,
    float* __restrict__ hout, float* __restrict__ xout) {
  __shared__ __align__(16) unsigned short inT[64 * 200];   // reused as float[64][100]
  __shared__ __align__(16) unsigned short tmpT[64 * 104];
  const int tid = threadIdx.x;
  const int nb = blockIdx.x * 64;
  {
    const int e = tid & 63, q = tid >> 6;
    const int node = nb + e;
    const int nc = node < NN ? node : NN - 1;
    const float* hr = h + (long)nc * 96 + q * 24;
    const float* wr = wmv + (long)nc * 96 + q * 24;
    unsigned* dh = (unsigned*)inT + e * 100 + q * 12;
    unsigned* dw = (unsigned*)inT + e * 100 + 48 + q * 12;
    #pragma unroll
    for (int c = 0; c < 6; ++c) {
      const float4 v = *(const float4*)(hr + c * 4);
      dh[c * 2]     = pk2(v.x, v.y);
      dh[c * 2 + 1] = pk2(v.z, v.w);
      const float4 u = *(const float4*)(wr + c * 4);
      dw[c * 2]     = pk2(u.x, u.y);
      dw[c * 2 + 1] = pk2(u.z, u.w);
    }
  }
  __syncthreads();
  const int l = tid & 63, w = tid >> 6, cg = l & 15, rg = l >> 4;
  {
    const unsigned short* ar = inT + (w * 16 + cg) * 200;
    short8v af[6];
    #pragma unroll
    for (int tk = 0; tk < 6; ++tk) af[tk] = *(const short8v*)(ar + tk * 32 + rg * 8);
    const short8v* Wp = (const short8v*)Wh1p;
    #pragma unroll
    for (int tn = 0; tn < 6; ++tn) {
      f32x4 acc = (f32x4){0.f, 0.f, 0.f, 0.f};
      #pragma unroll
      for (int tk = 0; tk < 6; ++tk)
        acc = __builtin_amdgcn_mfma_f32_16x16x32_bf16(af[tk], Wp[(tk * 6 + tn) * 64 + l], acc, 0, 0, 0);
      const int col = tn * 16 + cg;
      const float b = bh1[col];
      #pragma unroll
      for (int r = 0; r < 4; ++r)
        tmpT[(w * 16 + rg * 4 + r) * 104 + col] = f2bf(fmaxf(acc[r] + b, 0.f));
    }
  }
  __syncthreads();
  {
    float* oT = (float*)inT;
    const unsigned short* mr = tmpT + (w * 16 + cg) * 104;
    const short8v mf0 = *(const short8v*)(mr + rg * 8);
    const short8v mf1 = *(const short8v*)(mr + 32 + rg * 8);
    const short8v mf2 = *(const short8v*)(mr + 64 + rg * 8);
    const short8v* Wp = (const short8v*)Wh2p;
    #pragma unroll
    for (int tn = 0; tn < 6; ++tn) {
      f32x4 acc = (f32x4){0.f, 0.f, 0.f, 0.f};
      acc = __builtin_amdgcn_mfma_f32_16x16x32_bf16(mf0, Wp[(0 * 6 + tn) * 64 + l], acc, 0, 0, 0);
      acc = __builtin_amdgcn_mfma_f32_16x16x32_bf16(mf1, Wp[(1 * 6 + tn) * 64 + l], acc, 0, 0, 0);
      acc = __builtin_amdgcn_mfma_f32_16x16x32_bf16(mf2, Wp[(2 * 6 + tn) * 64 + l], acc, 0, 0, 0);
      const int col = tn * 16 + cg;
      const float b = bh2[col];
      #pragma unroll
      for (int r = 0; r < 4; ++r)
        oT[(w * 16 + rg * 4 + r) * 100 + col] = acc[r] + b;
    }
  }
  __syncthreads();
  {
    const int e = tid & 63, q = tid >> 6;
    const int node = nb + e;
    if (node < NN) {
      const float* src = (const float*)inT + e * 100 + q * 24;
      const float* hr = h + (size_t)node * 96 + q * 24;
      float* dst = hout + (size_t)node * 96 + q * 24;
      #pragma unroll
      for (int c = 0; c < 6; ++c) {
        const float4 s = *(const float4*)(src + c * 4);
        const float4 hv = *(const float4*)(hr + c * 4);
        *(float4*)(dst + c * 4) = make_float4(hv.x + s.x, hv.y + s.y, hv.z + s.z, hv.w + s.w);
      }
    }
  }
  if (tid < 64) {
    const int node = nb + tid;
    if (node < NN) {
      const int cnt = basep[node + 1] - basep[node];
      const float inv = cnt > 0 ? 1.f / (float)cnt : 0.f;
      const float4 s4 = *(const float4*)(svm + (long)node * 4);
      const float4 xv = *(const float4*)(x + (long)node * 4);
      *(float4*)(xout + (long)node * 4) =
          make_float4(xv.x + 0.005f * s4.x * inv, xv.y + 0.005f * s4.y * inv,
                      xv.z + 0.005f * s4.z * inv, xv.w + 0.005f * s4.w * inv);
    }
  }
}

// ---------------------------------------------------------------------------
extern "C" void kernel_launch(void* const* d_in, const int* in_sizes, int n_in,
                              void* d_out, int out_size, void* d_ws, size_t ws_size,
                              hipStream_t stream) {
  const float* x   = (const float*)d_in[0];
  const float* h   = (const float*)d_in[1];
  const int*   ei  = (const int*)d_in[2];
  const int*   ej  = (const int*)d_in[3];
  const float* We1 = (const float*)d_in[4];
  const float* be1 = (const float*)d_in[5];
  const float* We2 = (const float*)d_in[6];
  const float* be2 = (const float*)d_in[7];
  const float* Wm  = (const float*)d_in[8];
  const float* bm  = (const float*)d_in[9];
  const float* Wh1 = (const float*)d_in[10];
  const float* bh1 = (const float*)d_in[11];
  const float* Wh2 = (const float*)d_in[12];
  const float* bh2 = (const float*)d_in[13];
  const float* Wx1 = (const float*)d_in[14];
  const float* bx1 = (const float*)d_in[15];
  const float* Wx2 = (const float*)d_in[16];

  char* w = (char*)d_ws;
  unsigned short* Abf  = (unsigned short*)w;                 //  9.6 MB
  unsigned short* Bbf  = (unsigned short*)(w + 9600000);     //  9.6 MB
  float* WMv  = (float*)(w + 19200000);                      // 19.2 MB
  float* SvM  = (float*)(w + 38400000);                      //  0.8 MB
  int*   cnt  = (int*)(w + 39200000);                        //  0.2 MB
  int*   base = (int*)(w + 39400000);                        //  0.2 MB (+4)
  int*   curs = (int*)(w + 39600064);                        //  0.2 MB
  unsigned short* We2p = (unsigned short*)(w + 39800064);    // 18 KB
  unsigned short* Wx1p = (unsigned short*)(w + 39818496);    // 18 KB
  unsigned short* We1p = (unsigned short*)(w + 39836928);    // 36 KB
  unsigned short* Wh1p = (unsigned short*)(w + 39873792);    // 36 KB
  unsigned short* Wh2p = (unsigned short*)(w + 39910656);    // 18 KB
  int*   eis  = (int*)(w + 39929088);                        //  3.2 MB
  int*   ejs  = (int*)(w + 43129088);                        //  3.2 MB
  int*   pre  = (int*)(w + 46329088);                        //  0.2 MB
  int*   bsum = (int*)(w + 46529088);                        //  784 B
  int*   boff = (int*)(w + 46529872);                        //  784 B

  float* hout = (float*)d_out;
  float* xout = hout + 4800000;

  hipMemsetAsync(cnt, 0, NN * sizeof(int), stream);
  hipMemsetAsync(WMv, 0, (size_t)(4800000 + 200000) * sizeof(float), stream);
  khist<<<NE / 256, 256, 0, stream>>>(ei, cnt);
  kscanA<<<NB, 256, 0, stream>>>(cnt, pre, bsum);
  kscanB<<<1, 256, 0, stream>>>(bsum, boff);
  kscanC<<<NB, 256, 0, stream>>>(pre, boff, base, curs);
  kperm<<<NE / 256, 256, 0, stream>>>(ei, ej, curs, eis, ejs);
  kwprep<<<72, 256, 0, stream>>>(We1, We2, Wx1, Wh1, Wh2, We1p, We2p, Wx1p, Wh1p, Wh2p);
  k0_AB<<<782, 256, 0, stream>>>(h, We1p, Abf, Bbf);
  k1_edge<<<NE / TE, 256, 0, stream>>>(x, Abf, Bbf, eis, ejs, We1, be1, We2p, be2,
                                       Wm, bm, Wx1p, bx1, Wx2, WMv, SvM);
  k3ab<<<782, 256, 0, stream>>>(h, WMv, Wh1p, bh1, Wh2p, bh2, x, SvM, base, hout, xout);
}